// Round 6
// baseline (409.691 us; speedup 1.0000x reference)
//
#include <hip/hip_runtime.h>

// ---------------------------------------------------------------------------
// GCNnet: 3x GCNConv (40->40->80->128) + global max pool + MLP(128->512->2) + softmax
// N=100000 nodes, E=1600000 edges, G=512 graphs.
// Round 14 (= R13 resubmit; prior bench was an infra failure, not a kernel
// fault). R12's ILP-heavy gather (uint4 x8, 56 VGPR) halved occupancy
// (70->36%) and regressed. For a latency-bound kernel TLP is the hiding
// mechanism: revert to low-register body (ushort4, 4-edge unroll, ~30 VGPR)
// and DOUBLE THREADS instead: 2-way edge split. thread = (node, q, h);
// h in {0,1} takes edges j = h (mod 2); partners reduce via 5KB LDS +
// one __syncthreads. Block 320 so node groups (20/40 thr) never straddle.
// Same 8 rows/node in flight as R12, at R11 occupancy.
// ---------------------------------------------------------------------------

static inline int cdiv(long a, int b) { return (int)((a + b - 1) / b); }
static inline size_t align256(size_t x) { return (x + 255) & ~(size_t)255; }

#define FXSCALE 16777216.0f           // 2^24
#define SCHUNK  1024                  // elements per scan block
#define BKT_SHIFT 6                   // 64 nodes per bucket
#define MAXNB   2048                  // LDS histogram capacity (N <= 131072)
#define TB      256                   // histogram tiles

__device__ __forceinline__ float bf2f(unsigned short u) {
    return __uint_as_float(((unsigned int)u) << 16);
}
__device__ __forceinline__ unsigned short f2bf(float f) {   // round-nearest-even
    unsigned int u = __float_as_uint(f);
    return (unsigned short)((u + 0x7FFFu + ((u >> 16) & 1u)) >> 16);
}

// Pass A: per-tile LDS histogram over NB buckets (bucket = col>>6).
// gHist[tile][bucket]. Fused: x f32 -> bf16 convert into padded rows (stride 64).
__global__ __launch_bounds__(512)
void histA_kernel(const int* __restrict__ col, unsigned int* __restrict__ gHist,
                  int E, int NB, int chunk,
                  const float* __restrict__ x, ushort* __restrict__ xbf, long n4) {
    __shared__ unsigned int hist[MAXNB];
    int t = blockIdx.x;
    for (int i = threadIdx.x; i < NB; i += 512) hist[i] = 0u;
    __syncthreads();
    int s = t * chunk, e = min(s + chunk, E);
    for (int i = s + threadIdx.x; i < e; i += 512)
        atomicAdd(&hist[(unsigned int)col[i] >> BKT_SHIFT], 1u);
    // fused f2bf into padded layout: row = i/10, slot = i%10 -> xbf[row*64+slot*4]
    long gid = (long)t * 512 + threadIdx.x, gstride = (long)TB * 512;
    for (long i = gid; i < n4; i += gstride) {
        float4 v = ((const float4*)x)[i];
        long r = i / 10, c = i % 10;
        *(ushort4*)(xbf + r * 64 + c * 4) =
            make_ushort4(f2bf(v.x), f2bf(v.y), f2bf(v.z), f2bf(v.w));
    }
    __syncthreads();
    for (int b = threadIdx.x; b < NB; b += 512)
        gHist[(size_t)t * NB + b] = hist[b];
}

// scan phase A (histogram variant): per-block sums of the bucket-major view
// element i -> gHist[(i&255)*NB + (i>>8)]   (i = bucket*256 + tile)
__global__ void scanAH_kernel(const unsigned int* __restrict__ gHist,
                              int* __restrict__ blockSums, int TOT, int NB) {
    __shared__ int wred[4];
    int tid = threadIdx.x, lane = tid & 63, wid = tid >> 6;
    int i0 = blockIdx.x * SCHUNK + tid * 4;
    int s = 0;
#pragma unroll
    for (int k = 0; k < 4; ++k) {
        int i = i0 + k;
        if (i < TOT) s += (int)gHist[(size_t)(i & 255) * NB + (i >> 8)];
    }
#pragma unroll
    for (int off = 32; off > 0; off >>= 1) s += __shfl_down(s, off, 64);
    if (lane == 0) wred[wid] = s;
    __syncthreads();
    if (tid == 0) blockSums[blockIdx.x] = wred[0] + wred[1] + wred[2] + wred[3];
}

// scan phase B: one block, exclusive scan of blockSums[nb] (nb <= 1024);
// writes grand total into offs[N] (= E).
__global__ void scanB_kernel(int* __restrict__ blockSums, int* __restrict__ offs,
                             int nb, int N) {
    __shared__ int wsum[16];
    int tid = threadIdx.x, lane = tid & 63, wid = tid >> 6;
    int v = (tid < nb) ? blockSums[tid] : 0;
    int incl = v;
#pragma unroll
    for (int off = 1; off < 64; off <<= 1) {
        int t = __shfl_up(incl, off, 64);
        if (lane >= off) incl += t;
    }
    if (lane == 63) wsum[wid] = incl;
    __syncthreads();
    if (wid == 0 && lane < 16) {
        int w = wsum[lane];
        int ic = w;
#pragma unroll
        for (int off = 1; off < 16; off <<= 1) {
            int t = __shfl_up(ic, off, 64);
            if (lane >= off) ic += t;
        }
        wsum[lane] = ic - w;   // exclusive
    }
    __syncthreads();
    if (tid < nb) blockSums[tid] = wsum[wid] + incl - v;   // exclusive prefix
    if (tid == 1023) offs[N] = wsum[15] + incl;            // grand total
}

// scan phase C (histogram variant): local exclusive scan + block offset ->
// scanned[i] = global output cursor for (bucket = i>>8, tile = i&255)
__global__ void scanCH_kernel(const unsigned int* __restrict__ gHist,
                              const int* __restrict__ blockSums,
                              unsigned int* __restrict__ scanned, int TOT, int NB) {
    __shared__ int wsum[4];
    int tid = threadIdx.x, lane = tid & 63, wid = tid >> 6;
    int i0 = blockIdx.x * SCHUNK + tid * 4;
    int v0 = 0, v1 = 0, v2 = 0, v3 = 0;
    if (i0 + 0 < TOT) v0 = (int)gHist[(size_t)((i0 + 0) & 255) * NB + ((i0 + 0) >> 8)];
    if (i0 + 1 < TOT) v1 = (int)gHist[(size_t)((i0 + 1) & 255) * NB + ((i0 + 1) >> 8)];
    if (i0 + 2 < TOT) v2 = (int)gHist[(size_t)((i0 + 2) & 255) * NB + ((i0 + 2) >> 8)];
    if (i0 + 3 < TOT) v3 = (int)gHist[(size_t)((i0 + 3) & 255) * NB + ((i0 + 3) >> 8)];
    int sum = v0 + v1 + v2 + v3;
    int incl = sum;
#pragma unroll
    for (int off = 1; off < 64; off <<= 1) {
        int t = __shfl_up(incl, off, 64);
        if (lane >= off) incl += t;
    }
    if (lane == 63) wsum[wid] = incl;
    __syncthreads();
    if (tid == 0) {
        int c = 0;
#pragma unroll
        for (int k = 0; k < 4; ++k) { int t = wsum[k]; wsum[k] = c; c += t; }
    }
    __syncthreads();
    int pre = blockSums[blockIdx.x] + wsum[wid] + (incl - sum);
    if (i0 + 0 < TOT) scanned[i0 + 0] = (unsigned int)pre;
    if (i0 + 1 < TOT) scanned[i0 + 1] = (unsigned int)(pre + v0);
    if (i0 + 2 < TOT) scanned[i0 + 2] = (unsigned int)(pre + v0 + v1);
    if (i0 + 3 < TOT) scanned[i0 + 3] = (unsigned int)(pre + v0 + v1 + v2);
}

// Pass C: scatter edges into bucket-grouped semi[] via LDS cursors.
// semi[pos] = {row, col, wbits, 0}. Runs per (tile,bucket) are contiguous.
__global__ __launch_bounds__(512)
void scatterC_kernel(const int* __restrict__ row, const int* __restrict__ col,
                     const float* __restrict__ w,
                     const unsigned int* __restrict__ scanned,
                     int4* __restrict__ semi, int E, int NB, int chunk) {
    __shared__ unsigned int cur[MAXNB];
    int t = blockIdx.x;
    for (int b = threadIdx.x; b < NB; b += 512)
        cur[b] = scanned[(size_t)b * TB + t];
    __syncthreads();
    int s = t * chunk, e = min(s + chunk, E);
    for (int i = s + threadIdx.x; i < e; i += 512) {
        int c = col[i];
        unsigned int pos = atomicAdd(&cur[(unsigned int)c >> BKT_SHIFT], 1u);
        semi[pos] = make_int4(row[i], c, __float_as_int(w[i]), 0);
    }
}

// Pass D: one block per bucket (64 nodes). Fine counting sort by col&63,
// per-node weighted degree (fixed-point LDS atomics) -> perm {row,wbits},
// offs, dinv. All atomics LDS.
__global__ __launch_bounds__(256)
void fineD_kernel(const int4* __restrict__ semi, const unsigned int* __restrict__ scanned,
                  int* __restrict__ offs, float* __restrict__ dinv,
                  int2* __restrict__ perm, int E, int N, int NB) {
    __shared__ unsigned int cnt[64], cur[64], wsum[64];
    __shared__ int nodeOffs[64];
    int b = blockIdx.x, tid = threadIdx.x;
    int s = (int)scanned[(size_t)b * TB];
    int e = (b + 1 < NB) ? (int)scanned[(size_t)(b + 1) * TB] : E;
    if (tid < 64) { cnt[tid] = 0u; wsum[tid] = 0u; }
    __syncthreads();
    for (int i = s + tid; i < e; i += 256) {
        int4 v = semi[i];
        int c6 = v.y & 63;
        atomicAdd(&cnt[c6], 1u);
        atomicAdd(&wsum[c6], (unsigned int)llrintf(__int_as_float(v.z) * FXSCALE));
    }
    __syncthreads();
    if (tid < 64) {
        int v = (int)cnt[tid];
        int incl = v;
#pragma unroll
        for (int off = 1; off < 64; off <<= 1) {
            int u = __shfl_up(incl, off, 64);
            if (tid >= off) incl += u;
        }
        nodeOffs[tid] = incl - v;          // exclusive within bucket
        cur[tid] = (unsigned int)(incl - v);
    }
    __syncthreads();
    for (int i = s + tid; i < e; i += 256) {
        int4 v = semi[i];
        int c6 = v.y & 63;
        unsigned int r = atomicAdd(&cur[c6], 1u);
        perm[s + (int)r] = make_int2(v.x, v.z);   // {row, wbits}; norm in passE
    }
    if (tid < 64) {
        int node = (b << BKT_SHIFT) + tid;
        if (node < N) {
            offs[node] = s + nodeOffs[tid];
            float deg = (float)wsum[tid] * (1.0f / FXSCALE);
            dinv[node] = rsqrtf(deg + 1.0f);
        }
    }
    if (b == NB - 1 && tid == 0) offs[N] = E;
}

// Pass E: perm.y = dinv[row] * w * dinv[col]  (thread per destination node)
__global__ void normE_kernel(const int* __restrict__ offs, const float* __restrict__ dinv,
                             int2* __restrict__ perm, int N) {
    int n = blockIdx.x * blockDim.x + threadIdx.x;
    if (n >= N) return;
    int s = offs[n], e = offs[n + 1];
    float dc = dinv[n];
    for (int j = s; j < e; ++j) {
        int2 p = perm[j];
        float nm = dinv[p.x] * __int_as_float(p.y) * dc;
        perm[j] = make_int2(p.x, __float_as_int(nm));
    }
}

// agg[d] = sum_{e: col=d} H[row_e]*norm_e + dinv[d]^2*H[d]   (H bf16, padded rows)
// 2-way edge split: thread = (node, q, h); h takes edges j = h (mod 2);
// ushort4 (8B) loads, 4-edge unroll, 2 chains -> low VGPR, high occupancy;
// partner reduction via LDS. Block 320 (node groups of 2*TPN never straddle).
#define ACC4(A, U, M)                                                         \
    do {                                                                      \
        A.x += bf2f((U).x) * (M); A.y += bf2f((U).y) * (M);                   \
        A.z += bf2f((U).z) * (M); A.w += bf2f((U).w) * (M);                   \
    } while (0)

template<int F, int HSTR>
__global__ __launch_bounds__(320)
void gather_kernel(const int* __restrict__ offs, const int2* __restrict__ perm,
                   const ushort* __restrict__ H, const float* __restrict__ dinv,
                   float* __restrict__ agg, int N) {
    constexpr int TPN = F / 4;          // float4 feature slots
    constexpr int GRP = 2 * TPN;        // threads per node
    __shared__ float4 red[320];
    int idx = blockIdx.x * 320 + threadIdx.x;
    int node = idx / GRP, r = idx % GRP;
    int h = (r >= TPN) ? 1 : 0;
    int q = r - h * TPN;
    bool valid = node < N;
    int s = 0, e = 0;
    if (valid) { s = offs[node]; e = offs[node + 1]; }
    float4 a0 = make_float4(0.f, 0.f, 0.f, 0.f);
    float4 a1 = make_float4(0.f, 0.f, 0.f, 0.f);
    int j = s + h;
    for (; j + 6 < e; j += 8) {          // edges j, j+2, j+4, j+6 (stride 2)
        int2 p0 = perm[j + 0], p1 = perm[j + 2], p2 = perm[j + 4], p3 = perm[j + 6];
        ushort4 u0 = *(const ushort4*)(H + (long)p0.x * HSTR + q * 4);
        ushort4 u1 = *(const ushort4*)(H + (long)p1.x * HSTR + q * 4);
        ushort4 u2 = *(const ushort4*)(H + (long)p2.x * HSTR + q * 4);
        ushort4 u3 = *(const ushort4*)(H + (long)p3.x * HSTR + q * 4);
        ACC4(a0, u0, __int_as_float(p0.y));
        ACC4(a1, u1, __int_as_float(p1.y));
        ACC4(a0, u2, __int_as_float(p2.y));
        ACC4(a1, u3, __int_as_float(p3.y));
    }
    for (; j < e; j += 2) {
        int2 p = perm[j];
        ushort4 u = *(const ushort4*)(H + (long)p.x * HSTR + q * 4);
        ACC4(a0, u, __int_as_float(p.y));
    }
    if (valid && h == 0) {               // self-loop term on the h=0 half
        float di = dinv[node], d2 = di * di;
        ushort4 su = *(const ushort4*)(H + (long)node * HSTR + q * 4);
        ACC4(a0, su, d2);
    }
    a0.x += a1.x; a0.y += a1.y; a0.z += a1.z; a0.w += a1.w;
    red[threadIdx.x] = a0;
    __syncthreads();
    if (valid && h == 0) {
        float4 o = red[threadIdx.x + TPN];
        a0.x += o.x; a0.y += o.y; a0.z += o.z; a0.w += o.w;
        *(float4*)(agg + (long)node * F + q * 4) = a0;
    }
}

// out[N,FOUT] = relu(X[N,K] @ W[K,FOUT] + bias)
// thread = (NPT=4 consecutive nodes, 4 feats), q-minor lanes (coalesced X/W/out);
// W staged in LDS. BF16OUT: store ushort4 bf16 at row stride OSTR (padded).
// FUSE_POOL: hierarchical max-pool.
template<int K, int FOUT, int OSTR, int BLK, bool FUSE_POOL, bool BF16OUT>
__global__ __launch_bounds__(BLK)
void gemm_kernel(const float* __restrict__ X, const float* __restrict__ W,
                 const float* __restrict__ bias, void* __restrict__ out,
                 const int* __restrict__ batch, unsigned int* __restrict__ g, int N) {
    constexpr int NPT = 4;                 // nodes per thread
    constexpr int TPQ = FOUT / 4;          // feature-group slots
    constexpr int PSLOTS = BLK / TPQ;      // node-groups per block
    constexpr int NPB = PSLOTS * NPT;      // nodes per block
    __shared__ float wsm[K * FOUT];
    __shared__ unsigned int gma[FUSE_POOL ? 2 * FOUT : 1];
    __shared__ int gfirst;
    for (int i = threadIdx.x; i < K * FOUT; i += BLK) wsm[i] = W[i];
    if (FUSE_POOL) {
        if (threadIdx.x == 0) gfirst = batch[min((int)(blockIdx.x * NPB), N - 1)];
        for (int i = threadIdx.x; i < 2 * FOUT; i += BLK) gma[i] = 0u;
    }
    __syncthreads();

    int q = threadIdx.x % TPQ, p = threadIdx.x / TPQ;
    long nbase = (long)blockIdx.x * NPB + (long)p * NPT;

    float4 acc[NPT];
#pragma unroll
    for (int t = 0; t < NPT; ++t) acc[t] = make_float4(0.f, 0.f, 0.f, 0.f);

    const float* wq = wsm + q * 4;
#pragma unroll 4
    for (int i = 0; i < K / 4; ++i) {
        float4 xv[NPT];
#pragma unroll
        for (int t = 0; t < NPT; ++t) {
            long n = nbase + t; if (n >= N) n = N - 1;    // clamp (masked at store)
            xv[t] = *(const float4*)(X + n * K + i * 4);
        }
#pragma unroll
        for (int j = 0; j < 4; ++j) {
            float4 wv = *(const float4*)(wq + (i * 4 + j) * FOUT);
#pragma unroll
            for (int t = 0; t < NPT; ++t) {
                float v = ((const float*)&xv[t])[j];
                acc[t].x += v * wv.x; acc[t].y += v * wv.y;
                acc[t].z += v * wv.z; acc[t].w += v * wv.w;
            }
        }
    }

    float4 bv = *(const float4*)(bias + q * 4);
#pragma unroll
    for (int t = 0; t < NPT; ++t) {
        acc[t].x = fmaxf(acc[t].x + bv.x, 0.f);
        acc[t].y = fmaxf(acc[t].y + bv.y, 0.f);
        acc[t].z = fmaxf(acc[t].z + bv.z, 0.f);
        acc[t].w = fmaxf(acc[t].w + bv.w, 0.f);
    }

    if (!FUSE_POOL) {
        if (BF16OUT) {
            ushort* ob = (ushort*)out;
#pragma unroll
            for (int t = 0; t < NPT; ++t) {
                long n = nbase + t;
                if (n < N)
                    *(ushort4*)(ob + n * OSTR + q * 4) =
                        make_ushort4(f2bf(acc[t].x), f2bf(acc[t].y),
                                     f2bf(acc[t].z), f2bf(acc[t].w));
            }
        } else {
            float* of = (float*)out;
#pragma unroll
            for (int t = 0; t < NPT; ++t) {
                long n = nbase + t;
                if (n < N) *(float4*)(of + n * FOUT + q * 4) = acc[t];
            }
        }
        return;
    }

    // ---- hierarchical pool ----
#pragma unroll
    for (int t = 0; t < NPT; ++t) {
        long n = nbase + t;
        if (n < N) {
            unsigned int bx = __float_as_uint(acc[t].x), by = __float_as_uint(acc[t].y);
            unsigned int bz = __float_as_uint(acc[t].z), bw = __float_as_uint(acc[t].w);
            int rel = batch[n] - gfirst;
            if (rel < 2) {
                unsigned int* d = gma + rel * FOUT + q * 4;
                atomicMax(d + 0, bx); atomicMax(d + 1, by);
                atomicMax(d + 2, bz); atomicMax(d + 3, bw);
            } else {
                unsigned int* d = g + (long)batch[n] * FOUT + q * 4;
                atomicMax(d + 0, bx); atomicMax(d + 1, by);
                atomicMax(d + 2, bz); atomicMax(d + 3, bw);
            }
        }
    }
    __syncthreads();
    for (int i = threadIdx.x; i < 2 * FOUT; i += BLK) {
        unsigned int v = gma[i];
        if (v) atomicMax(&g[(long)(gfirst + i / FOUT) * FOUT + (i % FOUT)], v);
    }
}

// one block per graph: relu(g@Wfc1+bfc1) @ Wfc2 + bfc2 -> softmax
__global__ void fc_kernel(const float* __restrict__ g, const float* __restrict__ Wfc1,
                          const float* __restrict__ bfc1, const float* __restrict__ Wfc2,
                          const float* __restrict__ bfc2, float* __restrict__ out) {
    __shared__ float gs[128];
    __shared__ float red0[256], red1[256];
    int b = blockIdx.x, tid = threadIdx.x;
    if (tid < 128) gs[tid] = g[b * 128 + tid];
    __syncthreads();
    float h0 = bfc1[tid], h1 = bfc1[tid + 256];
    for (int k = 0; k < 128; ++k) {
        float gv = gs[k];
        h0 += gv * Wfc1[k * 512 + tid];
        h1 += gv * Wfc1[k * 512 + tid + 256];
    }
    h0 = fmaxf(h0, 0.f); h1 = fmaxf(h1, 0.f);
    red0[tid] = h0 * Wfc2[tid * 2 + 0] + h1 * Wfc2[(tid + 256) * 2 + 0];
    red1[tid] = h0 * Wfc2[tid * 2 + 1] + h1 * Wfc2[(tid + 256) * 2 + 1];
    __syncthreads();
    for (int s = 128; s > 0; s >>= 1) {
        if (tid < s) { red0[tid] += red0[tid + s]; red1[tid] += red1[tid + s]; }
        __syncthreads();
    }
    if (tid == 0) {
        float L0 = red0[0] + bfc2[0], L1 = red1[0] + bfc2[1];
        float m = fmaxf(L0, L1);
        float e0 = expf(L0 - m), e1 = expf(L1 - m);
        float inv = 1.f / (e0 + e1);
        out[b * 2 + 0] = e0 * inv;
        out[b * 2 + 1] = e1 * inv;
    }
}

extern "C" void kernel_launch(void* const* d_in, const int* in_sizes, int n_in,
                              void* d_out, int out_size, void* d_ws, size_t ws_size,
                              hipStream_t stream) {
    const float* x     = (const float*)d_in[0];
    const int*   ei    = (const int*)d_in[1];
    const float* ew    = (const float*)d_in[2];
    const int*   batch = (const int*)d_in[3];
    const float* W1    = (const float*)d_in[4];
    const float* b1    = (const float*)d_in[5];
    const float* W2    = (const float*)d_in[6];
    const float* b2    = (const float*)d_in[7];
    const float* W3    = (const float*)d_in[8];
    const float* b3    = (const float*)d_in[9];
    const float* Wfc1  = (const float*)d_in[10];
    const float* bfc1  = (const float*)d_in[11];
    const float* Wfc2  = (const float*)d_in[12];
    const float* bfc2  = (const float*)d_in[13];

    const int N = in_sizes[3];      // 100000
    const int E = in_sizes[2];      // 1600000
    const int* row = ei;
    const int* col = ei + E;

    char* ws = (char*)d_ws;
    float* dinv   = (float*)ws;              ws += align256((size_t)N * 4);
    int*   offs   = (int*)ws;                ws += align256((size_t)(N + 1) * 4);
    int*   bsums  = (int*)ws;                ws += align256((size_t)1024 * 4);
    int2*  perm   = (int2*)ws;               ws += align256((size_t)E * 8);
    float* bufA   = (float*)ws;              ws += align256((size_t)N * 128 * 4);  // agg f32
    ushort* bufH  = (ushort*)ws;             ws += align256((size_t)N * 96 * 2);   // H bf16 (padded)
    ushort* xbf   = (ushort*)ws;             ws += align256((size_t)N * 64 * 2);   // x bf16 (padded)
    float* g      = (float*)ws;              ws += align256((size_t)512 * 128 * 4);

    const int NB   = cdiv(N, 64);            // 1563 buckets (<= MAXNB)
    const int TOT  = NB * TB;                // (bucket, tile) cells = 400128
    const int chunkE = cdiv(E, TB);          // edges per tile = 6250
    const int nScanH = cdiv(TOT, SCHUNK);    // 391 (<= 1024)

    // transients aliased into bufA (51.2MB; all dead before gather1 writes bufA):
    // semi int4 (25.6MB) | gHist u32[TOT] (1.6MB) | scanned u32[TOT] (1.6MB)
    int4* semi = (int4*)bufA;
    unsigned int* gHist =
        (unsigned int*)((char*)bufA + align256((size_t)E * 16));
    unsigned int* scanned =
        (unsigned int*)((char*)gHist + align256((size_t)TOT * 4));

    const int B = 256;

    // --- atomic-free CSR build ---
    histA_kernel<<<TB, 512, 0, stream>>>(col, gHist, E, NB, chunkE,
                                         x, xbf, (long)N * 10);
    scanAH_kernel<<<nScanH, B, 0, stream>>>(gHist, bsums, TOT, NB);
    scanB_kernel<<<1, 1024, 0, stream>>>(bsums, offs, nScanH, N);
    scanCH_kernel<<<nScanH, B, 0, stream>>>(gHist, bsums, scanned, TOT, NB);
    scatterC_kernel<<<TB, 512, 0, stream>>>(row, col, ew, scanned, semi, E, NB, chunkE);
    fineD_kernel<<<NB, 256, 0, stream>>>(semi, scanned, offs, dinv, perm, E, N, NB);
    normE_kernel<<<cdiv(N, B), B, 0, stream>>>(offs, dinv, perm, N);

    // --- conv1: agg = A*x (40-wide bf16, stride 64), H1 = relu(agg@W1+b1) -> bufH ---
    gather_kernel<40, 64><<<cdiv((long)N * 20, 320), 320, 0, stream>>>(
        offs, perm, xbf, dinv, bufA, N);
    gemm_kernel<40, 40, 64, 320, false, true><<<cdiv(N, 128), 320, 0, stream>>>(
        bufA, W1, b1, bufH, nullptr, nullptr, N);

    // --- conv2: agg = A*H1 (40-wide, stride 64), H2 = relu(agg@W2+b2) -> bufH (stride 96) ---
    gather_kernel<40, 64><<<cdiv((long)N * 20, 320), 320, 0, stream>>>(
        offs, perm, bufH, dinv, bufA, N);
    gemm_kernel<40, 80, 96, 320, false, true><<<cdiv(N, 64), 320, 0, stream>>>(
        bufA, W2, b2, bufH, nullptr, nullptr, N);

    // --- conv3: agg = A*H2 (80-wide, stride 96), pool(relu(agg@W3 + b3)) -> g ---
    gather_kernel<80, 96><<<cdiv((long)N * 40, 320), 320, 0, stream>>>(
        offs, perm, bufH, dinv, bufA, N);
    hipMemsetAsync(g, 0, (size_t)512 * 128 * 4, stream);
    gemm_kernel<80, 128, 128, 256, true, false><<<cdiv(N, 32), 256, 0, stream>>>(
        bufA, W3, b3, nullptr, batch, (unsigned int*)g, N);

    // --- MLP + softmax ---
    fc_kernel<<<512, 256, 0, stream>>>(g, Wfc1, bfc1, Wfc2, bfc2, (float*)d_out);
}

// Round 7
// 383.562 us; speedup vs baseline: 1.0681x; 1.0681x over previous
//
#include <hip/hip_runtime.h>

// ---------------------------------------------------------------------------
// GCNnet: 3x GCNConv (40->40->80->128) + global max pool + MLP(128->512->2) + softmax
// N=100000 nodes, E=1600000 edges, G=512 graphs.
// Round 15: gather micro-variants exhausted (R11 simple=57us best; R12 ILP and
// R13 edge-split both regressed at constant FETCH) -> fabric-BW bound at
// ~3.7TB/s. Cut bytes instead of restructuring:
//  (a) revert gather to R11 exact form (unpadded rows, ushort4, 4-edge unroll);
//  (b) FUSE gemm1/gemm2 into the gathers via two-phase LDS (gather->LDS agg,
//      sync, gemm from LDS) -> removes 64MB of bufA round-trip + 2 launches;
//      agg rows padded to K+4 floats to avoid phase-2 bank conflicts;
//  (c) pack semi int4->int2 {row|c6<<17, wbits} -> saves ~38MB in build.
// conv3 stays split (W3=40KB LDS would crush gather occupancy).
// ---------------------------------------------------------------------------

static inline int cdiv(long a, int b) { return (int)((a + b - 1) / b); }
static inline size_t align256(size_t x) { return (x + 255) & ~(size_t)255; }

#define FXSCALE 16777216.0f           // 2^24
#define SCHUNK  1024                  // elements per scan block
#define BKT_SHIFT 6                   // 64 nodes per bucket
#define MAXNB   2048                  // LDS histogram capacity (N <= 131072)
#define TB      256                   // histogram tiles

__device__ __forceinline__ float bf2f(unsigned short u) {
    return __uint_as_float(((unsigned int)u) << 16);
}
__device__ __forceinline__ unsigned short f2bf(float f) {   // round-nearest-even
    unsigned int u = __float_as_uint(f);
    return (unsigned short)((u + 0x7FFFu + ((u >> 16) & 1u)) >> 16);
}

#define ACC4(A, U, M)                                                         \
    do {                                                                      \
        A.x += bf2f((U).x) * (M); A.y += bf2f((U).y) * (M);                   \
        A.z += bf2f((U).z) * (M); A.w += bf2f((U).w) * (M);                   \
    } while (0)

// Pass A: per-tile LDS histogram over NB buckets (bucket = col>>6).
// gHist[tile][bucket]. Fused: x f32 -> bf16 (unpadded rows, stride 40).
__global__ __launch_bounds__(512)
void histA_kernel(const int* __restrict__ col, unsigned int* __restrict__ gHist,
                  int E, int NB, int chunk,
                  const float* __restrict__ x, ushort* __restrict__ xbf, long n4) {
    __shared__ unsigned int hist[MAXNB];
    int t = blockIdx.x;
    for (int i = threadIdx.x; i < NB; i += 512) hist[i] = 0u;
    __syncthreads();
    int s = t * chunk, e = min(s + chunk, E);
    for (int i = s + threadIdx.x; i < e; i += 512)
        atomicAdd(&hist[(unsigned int)col[i] >> BKT_SHIFT], 1u);
    // fused f2bf: i/10 = row, i%10 = float4 slot -> xbf[row*40 + slot*4]
    long gid = (long)t * 512 + threadIdx.x, gstride = (long)TB * 512;
    for (long i = gid; i < n4; i += gstride) {
        float4 v = ((const float4*)x)[i];
        long r = i / 10, c = i % 10;
        *(ushort4*)(xbf + r * 40 + c * 4) =
            make_ushort4(f2bf(v.x), f2bf(v.y), f2bf(v.z), f2bf(v.w));
    }
    __syncthreads();
    for (int b = threadIdx.x; b < NB; b += 512)
        gHist[(size_t)t * NB + b] = hist[b];
}

// scan phase A (histogram variant): per-block sums of the bucket-major view
// element i -> gHist[(i&255)*NB + (i>>8)]   (i = bucket*256 + tile)
__global__ void scanAH_kernel(const unsigned int* __restrict__ gHist,
                              int* __restrict__ blockSums, int TOT, int NB) {
    __shared__ int wred[4];
    int tid = threadIdx.x, lane = tid & 63, wid = tid >> 6;
    int i0 = blockIdx.x * SCHUNK + tid * 4;
    int s = 0;
#pragma unroll
    for (int k = 0; k < 4; ++k) {
        int i = i0 + k;
        if (i < TOT) s += (int)gHist[(size_t)(i & 255) * NB + (i >> 8)];
    }
#pragma unroll
    for (int off = 32; off > 0; off >>= 1) s += __shfl_down(s, off, 64);
    if (lane == 0) wred[wid] = s;
    __syncthreads();
    if (tid == 0) blockSums[blockIdx.x] = wred[0] + wred[1] + wred[2] + wred[3];
}

// scan phase B: one block, exclusive scan of blockSums[nb] (nb <= 1024);
// writes grand total into offs[N] (= E).
__global__ void scanB_kernel(int* __restrict__ blockSums, int* __restrict__ offs,
                             int nb, int N) {
    __shared__ int wsum[16];
    int tid = threadIdx.x, lane = tid & 63, wid = tid >> 6;
    int v = (tid < nb) ? blockSums[tid] : 0;
    int incl = v;
#pragma unroll
    for (int off = 1; off < 64; off <<= 1) {
        int t = __shfl_up(incl, off, 64);
        if (lane >= off) incl += t;
    }
    if (lane == 63) wsum[wid] = incl;
    __syncthreads();
    if (wid == 0 && lane < 16) {
        int w = wsum[lane];
        int ic = w;
#pragma unroll
        for (int off = 1; off < 16; off <<= 1) {
            int t = __shfl_up(ic, off, 64);
            if (lane >= off) ic += t;
        }
        wsum[lane] = ic - w;   // exclusive
    }
    __syncthreads();
    if (tid < nb) blockSums[tid] = wsum[wid] + incl - v;   // exclusive prefix
    if (tid == 1023) offs[N] = wsum[15] + incl;            // grand total
}

// scan phase C (histogram variant): local exclusive scan + block offset ->
// scanned[i] = global output cursor for (bucket = i>>8, tile = i&255)
__global__ void scanCH_kernel(const unsigned int* __restrict__ gHist,
                              const int* __restrict__ blockSums,
                              unsigned int* __restrict__ scanned, int TOT, int NB) {
    __shared__ int wsum[4];
    int tid = threadIdx.x, lane = tid & 63, wid = tid >> 6;
    int i0 = blockIdx.x * SCHUNK + tid * 4;
    int v0 = 0, v1 = 0, v2 = 0, v3 = 0;
    if (i0 + 0 < TOT) v0 = (int)gHist[(size_t)((i0 + 0) & 255) * NB + ((i0 + 0) >> 8)];
    if (i0 + 1 < TOT) v1 = (int)gHist[(size_t)((i0 + 1) & 255) * NB + ((i0 + 1) >> 8)];
    if (i0 + 2 < TOT) v2 = (int)gHist[(size_t)((i0 + 2) & 255) * NB + ((i0 + 2) >> 8)];
    if (i0 + 3 < TOT) v3 = (int)gHist[(size_t)((i0 + 3) & 255) * NB + ((i0 + 3) >> 8)];
    int sum = v0 + v1 + v2 + v3;
    int incl = sum;
#pragma unroll
    for (int off = 1; off < 64; off <<= 1) {
        int t = __shfl_up(incl, off, 64);
        if (lane >= off) incl += t;
    }
    if (lane == 63) wsum[wid] = incl;
    __syncthreads();
    if (tid == 0) {
        int c = 0;
#pragma unroll
        for (int k = 0; k < 4; ++k) { int t = wsum[k]; wsum[k] = c; c += t; }
    }
    __syncthreads();
    int pre = blockSums[blockIdx.x] + wsum[wid] + (incl - sum);
    if (i0 + 0 < TOT) scanned[i0 + 0] = (unsigned int)pre;
    if (i0 + 1 < TOT) scanned[i0 + 1] = (unsigned int)(pre + v0);
    if (i0 + 2 < TOT) scanned[i0 + 2] = (unsigned int)(pre + v0 + v1);
    if (i0 + 3 < TOT) scanned[i0 + 3] = (unsigned int)(pre + v0 + v1 + v2);
}

// Pass C: scatter edges into bucket-grouped semi[] via LDS cursors.
// semi[pos] = {row | (col&63)<<17, wbits} (int2, row < 2^17).
__global__ __launch_bounds__(512)
void scatterC_kernel(const int* __restrict__ row, const int* __restrict__ col,
                     const float* __restrict__ w,
                     const unsigned int* __restrict__ scanned,
                     int2* __restrict__ semi, int E, int NB, int chunk) {
    __shared__ unsigned int cur[MAXNB];
    int t = blockIdx.x;
    for (int b = threadIdx.x; b < NB; b += 512)
        cur[b] = scanned[(size_t)b * TB + t];
    __syncthreads();
    int s = t * chunk, e = min(s + chunk, E);
    for (int i = s + threadIdx.x; i < e; i += 512) {
        int c = col[i];
        unsigned int pos = atomicAdd(&cur[(unsigned int)c >> BKT_SHIFT], 1u);
        semi[pos] = make_int2(row[i] | ((c & 63) << 17), __float_as_int(w[i]));
    }
}

// Pass D: one block per bucket (64 nodes). Fine counting sort by c6,
// per-node weighted degree (fixed-point LDS atomics) -> perm {row,wbits},
// offs, dinv. All atomics LDS.
__global__ __launch_bounds__(256)
void fineD_kernel(const int2* __restrict__ semi, const unsigned int* __restrict__ scanned,
                  int* __restrict__ offs, float* __restrict__ dinv,
                  int2* __restrict__ perm, int E, int N, int NB) {
    __shared__ unsigned int cnt[64], cur[64], wsum[64];
    __shared__ int nodeOffs[64];
    int b = blockIdx.x, tid = threadIdx.x;
    int s = (int)scanned[(size_t)b * TB];
    int e = (b + 1 < NB) ? (int)scanned[(size_t)(b + 1) * TB] : E;
    if (tid < 64) { cnt[tid] = 0u; wsum[tid] = 0u; }
    __syncthreads();
    for (int i = s + tid; i < e; i += 256) {
        int2 v = semi[i];
        int c6 = (v.x >> 17) & 63;
        atomicAdd(&cnt[c6], 1u);
        atomicAdd(&wsum[c6], (unsigned int)llrintf(__int_as_float(v.y) * FXSCALE));
    }
    __syncthreads();
    if (tid < 64) {
        int v = (int)cnt[tid];
        int incl = v;
#pragma unroll
        for (int off = 1; off < 64; off <<= 1) {
            int u = __shfl_up(incl, off, 64);
            if (tid >= off) incl += u;
        }
        nodeOffs[tid] = incl - v;          // exclusive within bucket
        cur[tid] = (unsigned int)(incl - v);
    }
    __syncthreads();
    for (int i = s + tid; i < e; i += 256) {
        int2 v = semi[i];
        int c6 = (v.x >> 17) & 63;
        unsigned int r = atomicAdd(&cur[c6], 1u);
        perm[s + (int)r] = make_int2(v.x & 0x1FFFF, v.y);   // {row, wbits}
    }
    if (tid < 64) {
        int node = (b << BKT_SHIFT) + tid;
        if (node < N) {
            offs[node] = s + nodeOffs[tid];
            float deg = (float)wsum[tid] * (1.0f / FXSCALE);
            dinv[node] = rsqrtf(deg + 1.0f);
        }
    }
    if (b == NB - 1 && tid == 0) offs[N] = E;
}

// Pass E: perm.y = dinv[row] * w * dinv[col]  (thread per destination node)
__global__ void normE_kernel(const int* __restrict__ offs, const float* __restrict__ dinv,
                             int2* __restrict__ perm, int N) {
    int n = blockIdx.x * blockDim.x + threadIdx.x;
    if (n >= N) return;
    int s = offs[n], e = offs[n + 1];
    float dc = dinv[n];
    for (int j = s; j < e; ++j) {
        int2 p = perm[j];
        float nm = dinv[p.x] * __int_as_float(p.y) * dc;
        perm[j] = make_int2(p.x, __float_as_int(nm));
    }
}

// R11 gather (best measured): thread = (node, 4 feats); 4-edge unroll,
// 2 chains, ushort4 loads, unpadded rows (stride F). Used for conv3 only.
template<int F>
__global__ void gather_kernel(const int* __restrict__ offs, const int2* __restrict__ perm,
                              const ushort* __restrict__ H, const float* __restrict__ dinv,
                              float* __restrict__ agg, int N) {
    constexpr int TPN = F / 4;
    int idx = blockIdx.x * blockDim.x + threadIdx.x;
    int node = idx / TPN, q = idx % TPN;
    if (node >= N) return;
    int s = offs[node], e = offs[node + 1];
    float4 a0 = make_float4(0.f, 0.f, 0.f, 0.f);
    float4 a1 = make_float4(0.f, 0.f, 0.f, 0.f);
    int j = s;
    for (; j + 4 <= e; j += 4) {
        int2 p0 = perm[j + 0], p1 = perm[j + 1], p2 = perm[j + 2], p3 = perm[j + 3];
        ushort4 u0 = *(const ushort4*)(H + (long)p0.x * F + q * 4);
        ushort4 u1 = *(const ushort4*)(H + (long)p1.x * F + q * 4);
        ushort4 u2 = *(const ushort4*)(H + (long)p2.x * F + q * 4);
        ushort4 u3 = *(const ushort4*)(H + (long)p3.x * F + q * 4);
        ACC4(a0, u0, __int_as_float(p0.y));
        ACC4(a1, u1, __int_as_float(p1.y));
        ACC4(a0, u2, __int_as_float(p2.y));
        ACC4(a1, u3, __int_as_float(p3.y));
    }
    for (; j < e; ++j) {
        int2 p = perm[j];
        ushort4 u = *(const ushort4*)(H + (long)p.x * F + q * 4);
        ACC4(a0, u, __int_as_float(p.y));
    }
    float di = dinv[node], d2 = di * di;
    ushort4 su = *(const ushort4*)(H + (long)node * F + q * 4);
    ACC4(a0, su, d2);
    a0.x += a1.x; a0.y += a1.y; a0.z += a1.z; a0.w += a1.w;
    *(float4*)(agg + (long)node * F + q * 4) = a0;
}

// Fused conv (conv1/conv2): phase1 = R11 gather into LDS agg (rows padded to
// K+4 floats vs phase-2 bank conflicts); sync; phase2 = gemm from LDS (same
// thread map as the proven gemm kernel: NPT=4 nodes, q-minor), relu, bf16 out.
// Removes the bufA global round-trip entirely.
template<int K, int FOUT, int NPB, int BLK>
__global__ __launch_bounds__(BLK)
void fused_conv_kernel(const int* __restrict__ offs, const int2* __restrict__ perm,
                       const ushort* __restrict__ H, const float* __restrict__ dinv,
                       const float* __restrict__ W, const float* __restrict__ bias,
                       ushort* __restrict__ out, int N) {
    constexpr int TPN = K / 4;
    constexpr int TPQ = FOUT / 4;
    constexpr int NPT = 4;
    constexpr int KP = K + 4;              // padded agg row (floats)
    static_assert((NPB * TPN) % BLK == 0, "phase1 tiling");
    static_assert((NPB / NPT) * TPQ == BLK, "phase2 tiling");
    __shared__ float wsm[K * FOUT];
    __shared__ float aggs[NPB * KP];
    for (int i = threadIdx.x; i < K * FOUT; i += BLK) wsm[i] = W[i];

    // ---- phase 1: gather into LDS ----
#pragma unroll
    for (int p0 = 0; p0 < NPB * TPN; p0 += BLK) {
        int p = p0 + threadIdx.x;
        int nl = p / TPN, q = p % TPN;
        int node = blockIdx.x * NPB + nl;
        float4 a0 = make_float4(0.f, 0.f, 0.f, 0.f);
        float4 a1 = make_float4(0.f, 0.f, 0.f, 0.f);
        if (node < N) {
            int s = offs[node], e = offs[node + 1];
            int j = s;
            for (; j + 4 <= e; j += 4) {
                int2 p0e = perm[j + 0], p1e = perm[j + 1];
                int2 p2e = perm[j + 2], p3e = perm[j + 3];
                ushort4 u0 = *(const ushort4*)(H + (long)p0e.x * K + q * 4);
                ushort4 u1 = *(const ushort4*)(H + (long)p1e.x * K + q * 4);
                ushort4 u2 = *(const ushort4*)(H + (long)p2e.x * K + q * 4);
                ushort4 u3 = *(const ushort4*)(H + (long)p3e.x * K + q * 4);
                ACC4(a0, u0, __int_as_float(p0e.y));
                ACC4(a1, u1, __int_as_float(p1e.y));
                ACC4(a0, u2, __int_as_float(p2e.y));
                ACC4(a1, u3, __int_as_float(p3e.y));
            }
            for (; j < e; ++j) {
                int2 pe = perm[j];
                ushort4 u = *(const ushort4*)(H + (long)pe.x * K + q * 4);
                ACC4(a0, u, __int_as_float(pe.y));
            }
            float di = dinv[node], d2 = di * di;
            ushort4 su = *(const ushort4*)(H + (long)node * K + q * 4);
            ACC4(a0, su, d2);
        }
        a0.x += a1.x; a0.y += a1.y; a0.z += a1.z; a0.w += a1.w;
        *(float4*)&aggs[nl * KP + q * 4] = a0;
    }
    __syncthreads();

    // ---- phase 2: gemm from LDS ----
    int q = threadIdx.x % TPQ, pg = threadIdx.x / TPQ;
    long nbase = (long)blockIdx.x * NPB + (long)pg * NPT;
    float4 acc[NPT];
#pragma unroll
    for (int t = 0; t < NPT; ++t) acc[t] = make_float4(0.f, 0.f, 0.f, 0.f);
    const float* wq = wsm + q * 4;
#pragma unroll 4
    for (int i = 0; i < K / 4; ++i) {
        float4 xv[NPT];
#pragma unroll
        for (int t = 0; t < NPT; ++t)
            xv[t] = *(const float4*)&aggs[(pg * NPT + t) * KP + i * 4];
#pragma unroll
        for (int j = 0; j < 4; ++j) {
            float4 wv = *(const float4*)(wq + (i * 4 + j) * FOUT);
#pragma unroll
            for (int t = 0; t < NPT; ++t) {
                float v = ((const float*)&xv[t])[j];
                acc[t].x += v * wv.x; acc[t].y += v * wv.y;
                acc[t].z += v * wv.z; acc[t].w += v * wv.w;
            }
        }
    }
    float4 bv = *(const float4*)(bias + q * 4);
#pragma unroll
    for (int t = 0; t < NPT; ++t) {
        long n = nbase + t;
        if (n < N) {
            float ox = fmaxf(acc[t].x + bv.x, 0.f);
            float oy = fmaxf(acc[t].y + bv.y, 0.f);
            float oz = fmaxf(acc[t].z + bv.z, 0.f);
            float ow = fmaxf(acc[t].w + bv.w, 0.f);
            *(ushort4*)(out + n * FOUT + q * 4) =
                make_ushort4(f2bf(ox), f2bf(oy), f2bf(oz), f2bf(ow));
        }
    }
}

// conv3 gemm + fused hierarchical max-pool (R11 form).
template<int K, int FOUT, int BLK, bool FUSE_POOL, bool BF16OUT>
__global__ __launch_bounds__(BLK)
void gemm_kernel(const float* __restrict__ X, const float* __restrict__ W,
                 const float* __restrict__ bias, void* __restrict__ out,
                 const int* __restrict__ batch, unsigned int* __restrict__ g, int N) {
    constexpr int NPT = 4;
    constexpr int TPQ = FOUT / 4;
    constexpr int PSLOTS = BLK / TPQ;
    constexpr int NPB = PSLOTS * NPT;
    __shared__ float wsm[K * FOUT];
    __shared__ unsigned int gma[FUSE_POOL ? 2 * FOUT : 1];
    __shared__ int gfirst;
    for (int i = threadIdx.x; i < K * FOUT; i += BLK) wsm[i] = W[i];
    if (FUSE_POOL) {
        if (threadIdx.x == 0) gfirst = batch[min((int)(blockIdx.x * NPB), N - 1)];
        for (int i = threadIdx.x; i < 2 * FOUT; i += BLK) gma[i] = 0u;
    }
    __syncthreads();

    int q = threadIdx.x % TPQ, p = threadIdx.x / TPQ;
    long nbase = (long)blockIdx.x * NPB + (long)p * NPT;

    float4 acc[NPT];
#pragma unroll
    for (int t = 0; t < NPT; ++t) acc[t] = make_float4(0.f, 0.f, 0.f, 0.f);

    const float* wq = wsm + q * 4;
#pragma unroll 4
    for (int i = 0; i < K / 4; ++i) {
        float4 xv[NPT];
#pragma unroll
        for (int t = 0; t < NPT; ++t) {
            long n = nbase + t; if (n >= N) n = N - 1;    // clamp (masked at store)
            xv[t] = *(const float4*)(X + n * K + i * 4);
        }
#pragma unroll
        for (int j = 0; j < 4; ++j) {
            float4 wv = *(const float4*)(wq + (i * 4 + j) * FOUT);
#pragma unroll
            for (int t = 0; t < NPT; ++t) {
                float v = ((const float*)&xv[t])[j];
                acc[t].x += v * wv.x; acc[t].y += v * wv.y;
                acc[t].z += v * wv.z; acc[t].w += v * wv.w;
            }
        }
    }

    float4 bv = *(const float4*)(bias + q * 4);
#pragma unroll
    for (int t = 0; t < NPT; ++t) {
        acc[t].x = fmaxf(acc[t].x + bv.x, 0.f);
        acc[t].y = fmaxf(acc[t].y + bv.y, 0.f);
        acc[t].z = fmaxf(acc[t].z + bv.z, 0.f);
        acc[t].w = fmaxf(acc[t].w + bv.w, 0.f);
    }

    if (!FUSE_POOL) {
        if (BF16OUT) {
            ushort* ob = (ushort*)out;
#pragma unroll
            for (int t = 0; t < NPT; ++t) {
                long n = nbase + t;
                if (n < N)
                    *(ushort4*)(ob + n * FOUT + q * 4) =
                        make_ushort4(f2bf(acc[t].x), f2bf(acc[t].y),
                                     f2bf(acc[t].z), f2bf(acc[t].w));
            }
        } else {
            float* of = (float*)out;
#pragma unroll
            for (int t = 0; t < NPT; ++t) {
                long n = nbase + t;
                if (n < N) *(float4*)(of + n * FOUT + q * 4) = acc[t];
            }
        }
        return;
    }

    // ---- hierarchical pool ----
#pragma unroll
    for (int t = 0; t < NPT; ++t) {
        long n = nbase + t;
        if (n < N) {
            unsigned int bx = __float_as_uint(acc[t].x), by = __float_as_uint(acc[t].y);
            unsigned int bz = __float_as_uint(acc[t].z), bw = __float_as_uint(acc[t].w);
            int rel = batch[n] - gfirst;
            if (rel < 2) {
                unsigned int* d = gma + rel * FOUT + q * 4;
                atomicMax(d + 0, bx); atomicMax(d + 1, by);
                atomicMax(d + 2, bz); atomicMax(d + 3, bw);
            } else {
                unsigned int* d = g + (long)batch[n] * FOUT + q * 4;
                atomicMax(d + 0, bx); atomicMax(d + 1, by);
                atomicMax(d + 2, bz); atomicMax(d + 3, bw);
            }
        }
    }
    __syncthreads();
    for (int i = threadIdx.x; i < 2 * FOUT; i += BLK) {
        unsigned int v = gma[i];
        if (v) atomicMax(&g[(long)(gfirst + i / FOUT) * FOUT + (i % FOUT)], v);
    }
}

// one block per graph: relu(g@Wfc1+bfc1) @ Wfc2 + bfc2 -> softmax
__global__ void fc_kernel(const float* __restrict__ g, const float* __restrict__ Wfc1,
                          const float* __restrict__ bfc1, const float* __restrict__ Wfc2,
                          const float* __restrict__ bfc2, float* __restrict__ out) {
    __shared__ float gs[128];
    __shared__ float red0[256], red1[256];
    int b = blockIdx.x, tid = threadIdx.x;
    if (tid < 128) gs[tid] = g[b * 128 + tid];
    __syncthreads();
    float h0 = bfc1[tid], h1 = bfc1[tid + 256];
    for (int k = 0; k < 128; ++k) {
        float gv = gs[k];
        h0 += gv * Wfc1[k * 512 + tid];
        h1 += gv * Wfc1[k * 512 + tid + 256];
    }
    h0 = fmaxf(h0, 0.f); h1 = fmaxf(h1, 0.f);
    red0[tid] = h0 * Wfc2[tid * 2 + 0] + h1 * Wfc2[(tid + 256) * 2 + 0];
    red1[tid] = h0 * Wfc2[tid * 2 + 1] + h1 * Wfc2[(tid + 256) * 2 + 1];
    __syncthreads();
    for (int s = 128; s > 0; s >>= 1) {
        if (tid < s) { red0[tid] += red0[tid + s]; red1[tid] += red1[tid + s]; }
        __syncthreads();
    }
    if (tid == 0) {
        float L0 = red0[0] + bfc2[0], L1 = red1[0] + bfc2[1];
        float m = fmaxf(L0, L1);
        float e0 = expf(L0 - m), e1 = expf(L1 - m);
        float inv = 1.f / (e0 + e1);
        out[b * 2 + 0] = e0 * inv;
        out[b * 2 + 1] = e1 * inv;
    }
}

extern "C" void kernel_launch(void* const* d_in, const int* in_sizes, int n_in,
                              void* d_out, int out_size, void* d_ws, size_t ws_size,
                              hipStream_t stream) {
    const float* x     = (const float*)d_in[0];
    const int*   ei    = (const int*)d_in[1];
    const float* ew    = (const float*)d_in[2];
    const int*   batch = (const int*)d_in[3];
    const float* W1    = (const float*)d_in[4];
    const float* b1    = (const float*)d_in[5];
    const float* W2    = (const float*)d_in[6];
    const float* b2    = (const float*)d_in[7];
    const float* W3    = (const float*)d_in[8];
    const float* b3    = (const float*)d_in[9];
    const float* Wfc1  = (const float*)d_in[10];
    const float* bfc1  = (const float*)d_in[11];
    const float* Wfc2  = (const float*)d_in[12];
    const float* bfc2  = (const float*)d_in[13];

    const int N = in_sizes[3];      // 100000
    const int E = in_sizes[2];      // 1600000
    const int* row = ei;
    const int* col = ei + E;

    char* ws = (char*)d_ws;
    float* dinv   = (float*)ws;              ws += align256((size_t)N * 4);
    int*   offs   = (int*)ws;                ws += align256((size_t)(N + 1) * 4);
    int*   bsums  = (int*)ws;                ws += align256((size_t)1024 * 4);
    int2*  perm   = (int2*)ws;               ws += align256((size_t)E * 8);
    float* bufA   = (float*)ws;              ws += align256((size_t)N * 128 * 4);  // agg f32 (conv3)
    ushort* bufH1 = (ushort*)ws;             ws += align256((size_t)N * 40 * 2);   // H1 bf16
    ushort* bufH2 = (ushort*)ws;             ws += align256((size_t)N * 80 * 2);   // H2 bf16
    ushort* xbf   = (ushort*)ws;             ws += align256((size_t)N * 40 * 2);   // x bf16
    float* g      = (float*)ws;              ws += align256((size_t)512 * 128 * 4);

    const int NB   = cdiv(N, 64);            // 1563 buckets (<= MAXNB)
    const int TOT  = NB * TB;                // (bucket, tile) cells = 400128
    const int chunkE = cdiv(E, TB);          // edges per tile = 6250
    const int nScanH = cdiv(TOT, SCHUNK);    // 391 (<= 1024)

    // transients aliased into bufA (51.2MB; all dead before gather3 writes bufA):
    // semi int2 (12.8MB) | gHist u32[TOT] (1.6MB) | scanned u32[TOT] (1.6MB)
    int2* semi = (int2*)bufA;
    unsigned int* gHist =
        (unsigned int*)((char*)bufA + align256((size_t)E * 8));
    unsigned int* scanned =
        (unsigned int*)((char*)gHist + align256((size_t)TOT * 4));

    const int B = 256;

    // --- atomic-free CSR build ---
    histA_kernel<<<TB, 512, 0, stream>>>(col, gHist, E, NB, chunkE,
                                         x, xbf, (long)N * 10);
    scanAH_kernel<<<nScanH, B, 0, stream>>>(gHist, bsums, TOT, NB);
    scanB_kernel<<<1, 1024, 0, stream>>>(bsums, offs, nScanH, N);
    scanCH_kernel<<<nScanH, B, 0, stream>>>(gHist, bsums, scanned, TOT, NB);
    scatterC_kernel<<<TB, 512, 0, stream>>>(row, col, ew, scanned, semi, E, NB, chunkE);
    fineD_kernel<<<NB, 256, 0, stream>>>(semi, scanned, offs, dinv, perm, E, N, NB);
    normE_kernel<<<cdiv(N, B), B, 0, stream>>>(offs, dinv, perm, N);

    // --- conv1 fused: H1 = relu((A*x)@W1 + b1) -> bufH1 (bf16) ---
    fused_conv_kernel<40, 40, 128, 320><<<cdiv(N, 128), 320, 0, stream>>>(
        offs, perm, xbf, dinv, W1, b1, bufH1, N);

    // --- conv2 fused: H2 = relu((A*H1)@W2 + b2) -> bufH2 (bf16) ---
    fused_conv_kernel<40, 80, 64, 320><<<cdiv(N, 64), 320, 0, stream>>>(
        offs, perm, bufH1, dinv, W2, b2, bufH2, N);

    // --- conv3: gather (R11) + gemm/pool ---
    gather_kernel<80><<<cdiv((long)N * 20, B), B, 0, stream>>>(
        offs, perm, bufH2, dinv, bufA, N);
    hipMemsetAsync(g, 0, (size_t)512 * 128 * 4, stream);
    gemm_kernel<80, 128, 256, true, false><<<cdiv(N, 32), 256, 0, stream>>>(
        bufA, W3, b3, nullptr, batch, (unsigned int*)g, N);

    // --- MLP + softmax ---
    fc_kernel<<<512, 256, 0, stream>>>(g, Wfc1, bfc1, Wfc2, bfc2, (float*)d_out);
}

// Round 8
// 372.382 us; speedup vs baseline: 1.1002x; 1.0300x over previous
//
#include <hip/hip_runtime.h>

// ---------------------------------------------------------------------------
// GCNnet: 3x GCNConv (40->40->80->128) + global max pool + MLP(128->512->2) + softmax
// N=100000 nodes, E=1600000 edges, G=512 graphs.
// Round 16: conv3 gemm exposed at 57us: occupancy 25% (40KB wsm -> 3 blk/CU)
// + 1.2M LDS bank conflicts (TPQ=32 -> lanes q,q+8,q+16,q+24 same bank,
// 4-way). Fix: split FOUT across blockIdx.y (COLS=64/block) -> wsm 20.5KB
// (2x blocks/CU) and TPQ=16 -> 2-way bank aliasing (free on gfx950).
// X re-read by 2nd col-half is an L2 broadcast (FETCH unchanged).
// Everything else identical to R15 (383.6us).
// ---------------------------------------------------------------------------

static inline int cdiv(long a, int b) { return (int)((a + b - 1) / b); }
static inline size_t align256(size_t x) { return (x + 255) & ~(size_t)255; }

#define FXSCALE 16777216.0f           // 2^24
#define SCHUNK  1024                  // elements per scan block
#define BKT_SHIFT 6                   // 64 nodes per bucket
#define MAXNB   2048                  // LDS histogram capacity (N <= 131072)
#define TB      256                   // histogram tiles

__device__ __forceinline__ float bf2f(unsigned short u) {
    return __uint_as_float(((unsigned int)u) << 16);
}
__device__ __forceinline__ unsigned short f2bf(float f) {   // round-nearest-even
    unsigned int u = __float_as_uint(f);
    return (unsigned short)((u + 0x7FFFu + ((u >> 16) & 1u)) >> 16);
}

#define ACC4(A, U, M)                                                         \
    do {                                                                      \
        A.x += bf2f((U).x) * (M); A.y += bf2f((U).y) * (M);                   \
        A.z += bf2f((U).z) * (M); A.w += bf2f((U).w) * (M);                   \
    } while (0)

// Pass A: per-tile LDS histogram over NB buckets (bucket = col>>6).
// gHist[tile][bucket]. Fused: x f32 -> bf16 (unpadded rows, stride 40).
__global__ __launch_bounds__(512)
void histA_kernel(const int* __restrict__ col, unsigned int* __restrict__ gHist,
                  int E, int NB, int chunk,
                  const float* __restrict__ x, ushort* __restrict__ xbf, long n4) {
    __shared__ unsigned int hist[MAXNB];
    int t = blockIdx.x;
    for (int i = threadIdx.x; i < NB; i += 512) hist[i] = 0u;
    __syncthreads();
    int s = t * chunk, e = min(s + chunk, E);
    for (int i = s + threadIdx.x; i < e; i += 512)
        atomicAdd(&hist[(unsigned int)col[i] >> BKT_SHIFT], 1u);
    // fused f2bf: i/10 = row, i%10 = float4 slot -> xbf[row*40 + slot*4]
    long gid = (long)t * 512 + threadIdx.x, gstride = (long)TB * 512;
    for (long i = gid; i < n4; i += gstride) {
        float4 v = ((const float4*)x)[i];
        long r = i / 10, c = i % 10;
        *(ushort4*)(xbf + r * 40 + c * 4) =
            make_ushort4(f2bf(v.x), f2bf(v.y), f2bf(v.z), f2bf(v.w));
    }
    __syncthreads();
    for (int b = threadIdx.x; b < NB; b += 512)
        gHist[(size_t)t * NB + b] = hist[b];
}

// scan phase A (histogram variant): per-block sums of the bucket-major view
// element i -> gHist[(i&255)*NB + (i>>8)]   (i = bucket*256 + tile)
__global__ void scanAH_kernel(const unsigned int* __restrict__ gHist,
                              int* __restrict__ blockSums, int TOT, int NB) {
    __shared__ int wred[4];
    int tid = threadIdx.x, lane = tid & 63, wid = tid >> 6;
    int i0 = blockIdx.x * SCHUNK + tid * 4;
    int s = 0;
#pragma unroll
    for (int k = 0; k < 4; ++k) {
        int i = i0 + k;
        if (i < TOT) s += (int)gHist[(size_t)(i & 255) * NB + (i >> 8)];
    }
#pragma unroll
    for (int off = 32; off > 0; off >>= 1) s += __shfl_down(s, off, 64);
    if (lane == 0) wred[wid] = s;
    __syncthreads();
    if (tid == 0) blockSums[blockIdx.x] = wred[0] + wred[1] + wred[2] + wred[3];
}

// scan phase B: one block, exclusive scan of blockSums[nb] (nb <= 1024);
// writes grand total into offs[N] (= E).
__global__ void scanB_kernel(int* __restrict__ blockSums, int* __restrict__ offs,
                             int nb, int N) {
    __shared__ int wsum[16];
    int tid = threadIdx.x, lane = tid & 63, wid = tid >> 6;
    int v = (tid < nb) ? blockSums[tid] : 0;
    int incl = v;
#pragma unroll
    for (int off = 1; off < 64; off <<= 1) {
        int t = __shfl_up(incl, off, 64);
        if (lane >= off) incl += t;
    }
    if (lane == 63) wsum[wid] = incl;
    __syncthreads();
    if (wid == 0 && lane < 16) {
        int w = wsum[lane];
        int ic = w;
#pragma unroll
        for (int off = 1; off < 16; off <<= 1) {
            int t = __shfl_up(ic, off, 64);
            if (lane >= off) ic += t;
        }
        wsum[lane] = ic - w;   // exclusive
    }
    __syncthreads();
    if (tid < nb) blockSums[tid] = wsum[wid] + incl - v;   // exclusive prefix
    if (tid == 1023) offs[N] = wsum[15] + incl;            // grand total
}

// scan phase C (histogram variant): local exclusive scan + block offset ->
// scanned[i] = global output cursor for (bucket = i>>8, tile = i&255)
__global__ void scanCH_kernel(const unsigned int* __restrict__ gHist,
                              const int* __restrict__ blockSums,
                              unsigned int* __restrict__ scanned, int TOT, int NB) {
    __shared__ int wsum[4];
    int tid = threadIdx.x, lane = tid & 63, wid = tid >> 6;
    int i0 = blockIdx.x * SCHUNK + tid * 4;
    int v0 = 0, v1 = 0, v2 = 0, v3 = 0;
    if (i0 + 0 < TOT) v0 = (int)gHist[(size_t)((i0 + 0) & 255) * NB + ((i0 + 0) >> 8)];
    if (i0 + 1 < TOT) v1 = (int)gHist[(size_t)((i0 + 1) & 255) * NB + ((i0 + 1) >> 8)];
    if (i0 + 2 < TOT) v2 = (int)gHist[(size_t)((i0 + 2) & 255) * NB + ((i0 + 2) >> 8)];
    if (i0 + 3 < TOT) v3 = (int)gHist[(size_t)((i0 + 3) & 255) * NB + ((i0 + 3) >> 8)];
    int sum = v0 + v1 + v2 + v3;
    int incl = sum;
#pragma unroll
    for (int off = 1; off < 64; off <<= 1) {
        int t = __shfl_up(incl, off, 64);
        if (lane >= off) incl += t;
    }
    if (lane == 63) wsum[wid] = incl;
    __syncthreads();
    if (tid == 0) {
        int c = 0;
#pragma unroll
        for (int k = 0; k < 4; ++k) { int t = wsum[k]; wsum[k] = c; c += t; }
    }
    __syncthreads();
    int pre = blockSums[blockIdx.x] + wsum[wid] + (incl - sum);
    if (i0 + 0 < TOT) scanned[i0 + 0] = (unsigned int)pre;
    if (i0 + 1 < TOT) scanned[i0 + 1] = (unsigned int)(pre + v0);
    if (i0 + 2 < TOT) scanned[i0 + 2] = (unsigned int)(pre + v0 + v1);
    if (i0 + 3 < TOT) scanned[i0 + 3] = (unsigned int)(pre + v0 + v1 + v2);
}

// Pass C: scatter edges into bucket-grouped semi[] via LDS cursors.
// semi[pos] = {row | (col&63)<<17, wbits} (int2, row < 2^17).
__global__ __launch_bounds__(512)
void scatterC_kernel(const int* __restrict__ row, const int* __restrict__ col,
                     const float* __restrict__ w,
                     const unsigned int* __restrict__ scanned,
                     int2* __restrict__ semi, int E, int NB, int chunk) {
    __shared__ unsigned int cur[MAXNB];
    int t = blockIdx.x;
    for (int b = threadIdx.x; b < NB; b += 512)
        cur[b] = scanned[(size_t)b * TB + t];
    __syncthreads();
    int s = t * chunk, e = min(s + chunk, E);
    for (int i = s + threadIdx.x; i < e; i += 512) {
        int c = col[i];
        unsigned int pos = atomicAdd(&cur[(unsigned int)c >> BKT_SHIFT], 1u);
        semi[pos] = make_int2(row[i] | ((c & 63) << 17), __float_as_int(w[i]));
    }
}

// Pass D: one block per bucket (64 nodes). Fine counting sort by c6,
// per-node weighted degree (fixed-point LDS atomics) -> perm {row,wbits},
// offs, dinv. All atomics LDS.
__global__ __launch_bounds__(256)
void fineD_kernel(const int2* __restrict__ semi, const unsigned int* __restrict__ scanned,
                  int* __restrict__ offs, float* __restrict__ dinv,
                  int2* __restrict__ perm, int E, int N, int NB) {
    __shared__ unsigned int cnt[64], cur[64], wsum[64];
    __shared__ int nodeOffs[64];
    int b = blockIdx.x, tid = threadIdx.x;
    int s = (int)scanned[(size_t)b * TB];
    int e = (b + 1 < NB) ? (int)scanned[(size_t)(b + 1) * TB] : E;
    if (tid < 64) { cnt[tid] = 0u; wsum[tid] = 0u; }
    __syncthreads();
    for (int i = s + tid; i < e; i += 256) {
        int2 v = semi[i];
        int c6 = (v.x >> 17) & 63;
        atomicAdd(&cnt[c6], 1u);
        atomicAdd(&wsum[c6], (unsigned int)llrintf(__int_as_float(v.y) * FXSCALE));
    }
    __syncthreads();
    if (tid < 64) {
        int v = (int)cnt[tid];
        int incl = v;
#pragma unroll
        for (int off = 1; off < 64; off <<= 1) {
            int u = __shfl_up(incl, off, 64);
            if (tid >= off) incl += u;
        }
        nodeOffs[tid] = incl - v;          // exclusive within bucket
        cur[tid] = (unsigned int)(incl - v);
    }
    __syncthreads();
    for (int i = s + tid; i < e; i += 256) {
        int2 v = semi[i];
        int c6 = (v.x >> 17) & 63;
        unsigned int r = atomicAdd(&cur[c6], 1u);
        perm[s + (int)r] = make_int2(v.x & 0x1FFFF, v.y);   // {row, wbits}
    }
    if (tid < 64) {
        int node = (b << BKT_SHIFT) + tid;
        if (node < N) {
            offs[node] = s + nodeOffs[tid];
            float deg = (float)wsum[tid] * (1.0f / FXSCALE);
            dinv[node] = rsqrtf(deg + 1.0f);
        }
    }
    if (b == NB - 1 && tid == 0) offs[N] = E;
}

// Pass E: perm.y = dinv[row] * w * dinv[col]  (thread per destination node)
__global__ void normE_kernel(const int* __restrict__ offs, const float* __restrict__ dinv,
                             int2* __restrict__ perm, int N) {
    int n = blockIdx.x * blockDim.x + threadIdx.x;
    if (n >= N) return;
    int s = offs[n], e = offs[n + 1];
    float dc = dinv[n];
    for (int j = s; j < e; ++j) {
        int2 p = perm[j];
        float nm = dinv[p.x] * __int_as_float(p.y) * dc;
        perm[j] = make_int2(p.x, __float_as_int(nm));
    }
}

// R11 gather (best measured): thread = (node, 4 feats); 4-edge unroll,
// 2 chains, ushort4 loads, unpadded rows (stride F). Used for conv3 only.
template<int F>
__global__ void gather_kernel(const int* __restrict__ offs, const int2* __restrict__ perm,
                              const ushort* __restrict__ H, const float* __restrict__ dinv,
                              float* __restrict__ agg, int N) {
    constexpr int TPN = F / 4;
    int idx = blockIdx.x * blockDim.x + threadIdx.x;
    int node = idx / TPN, q = idx % TPN;
    if (node >= N) return;
    int s = offs[node], e = offs[node + 1];
    float4 a0 = make_float4(0.f, 0.f, 0.f, 0.f);
    float4 a1 = make_float4(0.f, 0.f, 0.f, 0.f);
    int j = s;
    for (; j + 4 <= e; j += 4) {
        int2 p0 = perm[j + 0], p1 = perm[j + 1], p2 = perm[j + 2], p3 = perm[j + 3];
        ushort4 u0 = *(const ushort4*)(H + (long)p0.x * F + q * 4);
        ushort4 u1 = *(const ushort4*)(H + (long)p1.x * F + q * 4);
        ushort4 u2 = *(const ushort4*)(H + (long)p2.x * F + q * 4);
        ushort4 u3 = *(const ushort4*)(H + (long)p3.x * F + q * 4);
        ACC4(a0, u0, __int_as_float(p0.y));
        ACC4(a1, u1, __int_as_float(p1.y));
        ACC4(a0, u2, __int_as_float(p2.y));
        ACC4(a1, u3, __int_as_float(p3.y));
    }
    for (; j < e; ++j) {
        int2 p = perm[j];
        ushort4 u = *(const ushort4*)(H + (long)p.x * F + q * 4);
        ACC4(a0, u, __int_as_float(p.y));
    }
    float di = dinv[node], d2 = di * di;
    ushort4 su = *(const ushort4*)(H + (long)node * F + q * 4);
    ACC4(a0, su, d2);
    a0.x += a1.x; a0.y += a1.y; a0.z += a1.z; a0.w += a1.w;
    *(float4*)(agg + (long)node * F + q * 4) = a0;
}

// Fused conv (conv1/conv2): phase1 = R11 gather into LDS agg (rows padded to
// K+4 floats vs phase-2 bank conflicts); sync; phase2 = gemm from LDS, relu,
// bf16 out. Removes the bufA global round-trip entirely.
template<int K, int FOUT, int NPB, int BLK>
__global__ __launch_bounds__(BLK)
void fused_conv_kernel(const int* __restrict__ offs, const int2* __restrict__ perm,
                       const ushort* __restrict__ H, const float* __restrict__ dinv,
                       const float* __restrict__ W, const float* __restrict__ bias,
                       ushort* __restrict__ out, int N) {
    constexpr int TPN = K / 4;
    constexpr int TPQ = FOUT / 4;
    constexpr int NPT = 4;
    constexpr int KP = K + 4;              // padded agg row (floats)
    static_assert((NPB * TPN) % BLK == 0, "phase1 tiling");
    static_assert((NPB / NPT) * TPQ == BLK, "phase2 tiling");
    __shared__ float wsm[K * FOUT];
    __shared__ float aggs[NPB * KP];
    for (int i = threadIdx.x; i < K * FOUT; i += BLK) wsm[i] = W[i];

    // ---- phase 1: gather into LDS ----
#pragma unroll
    for (int p0 = 0; p0 < NPB * TPN; p0 += BLK) {
        int p = p0 + threadIdx.x;
        int nl = p / TPN, q = p % TPN;
        int node = blockIdx.x * NPB + nl;
        float4 a0 = make_float4(0.f, 0.f, 0.f, 0.f);
        float4 a1 = make_float4(0.f, 0.f, 0.f, 0.f);
        if (node < N) {
            int s = offs[node], e = offs[node + 1];
            int j = s;
            for (; j + 4 <= e; j += 4) {
                int2 p0e = perm[j + 0], p1e = perm[j + 1];
                int2 p2e = perm[j + 2], p3e = perm[j + 3];
                ushort4 u0 = *(const ushort4*)(H + (long)p0e.x * K + q * 4);
                ushort4 u1 = *(const ushort4*)(H + (long)p1e.x * K + q * 4);
                ushort4 u2 = *(const ushort4*)(H + (long)p2e.x * K + q * 4);
                ushort4 u3 = *(const ushort4*)(H + (long)p3e.x * K + q * 4);
                ACC4(a0, u0, __int_as_float(p0e.y));
                ACC4(a1, u1, __int_as_float(p1e.y));
                ACC4(a0, u2, __int_as_float(p2e.y));
                ACC4(a1, u3, __int_as_float(p3e.y));
            }
            for (; j < e; ++j) {
                int2 pe = perm[j];
                ushort4 u = *(const ushort4*)(H + (long)pe.x * K + q * 4);
                ACC4(a0, u, __int_as_float(pe.y));
            }
            float di = dinv[node], d2 = di * di;
            ushort4 su = *(const ushort4*)(H + (long)node * K + q * 4);
            ACC4(a0, su, d2);
        }
        a0.x += a1.x; a0.y += a1.y; a0.z += a1.z; a0.w += a1.w;
        *(float4*)&aggs[nl * KP + q * 4] = a0;
    }
    __syncthreads();

    // ---- phase 2: gemm from LDS ----
    int q = threadIdx.x % TPQ, pg = threadIdx.x / TPQ;
    long nbase = (long)blockIdx.x * NPB + (long)pg * NPT;
    float4 acc[NPT];
#pragma unroll
    for (int t = 0; t < NPT; ++t) acc[t] = make_float4(0.f, 0.f, 0.f, 0.f);
    const float* wq = wsm + q * 4;
#pragma unroll 4
    for (int i = 0; i < K / 4; ++i) {
        float4 xv[NPT];
#pragma unroll
        for (int t = 0; t < NPT; ++t)
            xv[t] = *(const float4*)&aggs[(pg * NPT + t) * KP + i * 4];
#pragma unroll
        for (int j = 0; j < 4; ++j) {
            float4 wv = *(const float4*)(wq + (i * 4 + j) * FOUT);
#pragma unroll
            for (int t = 0; t < NPT; ++t) {
                float v = ((const float*)&xv[t])[j];
                acc[t].x += v * wv.x; acc[t].y += v * wv.y;
                acc[t].z += v * wv.z; acc[t].w += v * wv.w;
            }
        }
    }
    float4 bv = *(const float4*)(bias + q * 4);
#pragma unroll
    for (int t = 0; t < NPT; ++t) {
        long n = nbase + t;
        if (n < N) {
            float ox = fmaxf(acc[t].x + bv.x, 0.f);
            float oy = fmaxf(acc[t].y + bv.y, 0.f);
            float oz = fmaxf(acc[t].z + bv.z, 0.f);
            float ow = fmaxf(acc[t].w + bv.w, 0.f);
            *(ushort4*)(out + n * FOUT + q * 4) =
                make_ushort4(f2bf(ox), f2bf(oy), f2bf(oz), f2bf(ow));
        }
    }
}

// conv3 gemm + fused hierarchical max-pool, FOUT split across blockIdx.y:
// each block computes COLS columns (wsm = K*COLS floats -> 2x occupancy,
// TPQ = COLS/4 = 16 -> 2-way LDS bank aliasing = free).
template<int K, int FOUT, int COLS, int BLK>
__global__ __launch_bounds__(BLK)
void gemm_pool_kernel(const float* __restrict__ X, const float* __restrict__ W,
                      const float* __restrict__ bias,
                      const int* __restrict__ batch, unsigned int* __restrict__ g,
                      int N) {
    constexpr int NPT = 4;
    constexpr int TPQ = COLS / 4;
    constexpr int PSLOTS = BLK / TPQ;
    constexpr int NPB = PSLOTS * NPT;
    __shared__ float wsm[K * COLS];
    __shared__ unsigned int gma[2 * COLS];
    __shared__ int gfirst;
    int col0 = blockIdx.y * COLS;
    for (int i = threadIdx.x; i < K * COLS; i += BLK)
        wsm[i] = W[(i / COLS) * FOUT + col0 + (i % COLS)];
    if (threadIdx.x == 0) gfirst = batch[min((int)(blockIdx.x * NPB), N - 1)];
    for (int i = threadIdx.x; i < 2 * COLS; i += BLK) gma[i] = 0u;
    __syncthreads();

    int q = threadIdx.x % TPQ, p = threadIdx.x / TPQ;
    long nbase = (long)blockIdx.x * NPB + (long)p * NPT;

    float4 acc[NPT];
#pragma unroll
    for (int t = 0; t < NPT; ++t) acc[t] = make_float4(0.f, 0.f, 0.f, 0.f);

    const float* wq = wsm + q * 4;
#pragma unroll 4
    for (int i = 0; i < K / 4; ++i) {
        float4 xv[NPT];
#pragma unroll
        for (int t = 0; t < NPT; ++t) {
            long n = nbase + t; if (n >= N) n = N - 1;    // clamp (masked at store)
            xv[t] = *(const float4*)(X + n * K + i * 4);
        }
#pragma unroll
        for (int j = 0; j < 4; ++j) {
            float4 wv = *(const float4*)(wq + (i * 4 + j) * COLS);
#pragma unroll
            for (int t = 0; t < NPT; ++t) {
                float v = ((const float*)&xv[t])[j];
                acc[t].x += v * wv.x; acc[t].y += v * wv.y;
                acc[t].z += v * wv.z; acc[t].w += v * wv.w;
            }
        }
    }

    float4 bv = *(const float4*)(bias + col0 + q * 4);
#pragma unroll
    for (int t = 0; t < NPT; ++t) {
        acc[t].x = fmaxf(acc[t].x + bv.x, 0.f);
        acc[t].y = fmaxf(acc[t].y + bv.y, 0.f);
        acc[t].z = fmaxf(acc[t].z + bv.z, 0.f);
        acc[t].w = fmaxf(acc[t].w + bv.w, 0.f);
    }

    // ---- hierarchical pool (2-graph LDS window, col0 offset) ----
#pragma unroll
    for (int t = 0; t < NPT; ++t) {
        long n = nbase + t;
        if (n < N) {
            unsigned int bx = __float_as_uint(acc[t].x), by = __float_as_uint(acc[t].y);
            unsigned int bz = __float_as_uint(acc[t].z), bw = __float_as_uint(acc[t].w);
            int rel = batch[n] - gfirst;
            if (rel < 2) {
                unsigned int* d = gma + rel * COLS + q * 4;
                atomicMax(d + 0, bx); atomicMax(d + 1, by);
                atomicMax(d + 2, bz); atomicMax(d + 3, bw);
            } else {
                unsigned int* d = g + (long)batch[n] * FOUT + col0 + q * 4;
                atomicMax(d + 0, bx); atomicMax(d + 1, by);
                atomicMax(d + 2, bz); atomicMax(d + 3, bw);
            }
        }
    }
    __syncthreads();
    for (int i = threadIdx.x; i < 2 * COLS; i += BLK) {
        unsigned int v = gma[i];
        if (v) atomicMax(&g[(long)(gfirst + i / COLS) * FOUT + col0 + (i % COLS)], v);
    }
}

// one block per graph: relu(g@Wfc1+bfc1) @ Wfc2 + bfc2 -> softmax
__global__ void fc_kernel(const float* __restrict__ g, const float* __restrict__ Wfc1,
                          const float* __restrict__ bfc1, const float* __restrict__ Wfc2,
                          const float* __restrict__ bfc2, float* __restrict__ out) {
    __shared__ float gs[128];
    __shared__ float red0[256], red1[256];
    int b = blockIdx.x, tid = threadIdx.x;
    if (tid < 128) gs[tid] = g[b * 128 + tid];
    __syncthreads();
    float h0 = bfc1[tid], h1 = bfc1[tid + 256];
    for (int k = 0; k < 128; ++k) {
        float gv = gs[k];
        h0 += gv * Wfc1[k * 512 + tid];
        h1 += gv * Wfc1[k * 512 + tid + 256];
    }
    h0 = fmaxf(h0, 0.f); h1 = fmaxf(h1, 0.f);
    red0[tid] = h0 * Wfc2[tid * 2 + 0] + h1 * Wfc2[(tid + 256) * 2 + 0];
    red1[tid] = h0 * Wfc2[tid * 2 + 1] + h1 * Wfc2[(tid + 256) * 2 + 1];
    __syncthreads();
    for (int s = 128; s > 0; s >>= 1) {
        if (tid < s) { red0[tid] += red0[tid + s]; red1[tid] += red1[tid + s]; }
        __syncthreads();
    }
    if (tid == 0) {
        float L0 = red0[0] + bfc2[0], L1 = red1[0] + bfc2[1];
        float m = fmaxf(L0, L1);
        float e0 = expf(L0 - m), e1 = expf(L1 - m);
        float inv = 1.f / (e0 + e1);
        out[b * 2 + 0] = e0 * inv;
        out[b * 2 + 1] = e1 * inv;
    }
}

extern "C" void kernel_launch(void* const* d_in, const int* in_sizes, int n_in,
                              void* d_out, int out_size, void* d_ws, size_t ws_size,
                              hipStream_t stream) {
    const float* x     = (const float*)d_in[0];
    const int*   ei    = (const int*)d_in[1];
    const float* ew    = (const float*)d_in[2];
    const int*   batch = (const int*)d_in[3];
    const float* W1    = (const float*)d_in[4];
    const float* b1    = (const float*)d_in[5];
    const float* W2    = (const float*)d_in[6];
    const float* b2    = (const float*)d_in[7];
    const float* W3    = (const float*)d_in[8];
    const float* b3    = (const float*)d_in[9];
    const float* Wfc1  = (const float*)d_in[10];
    const float* bfc1  = (const float*)d_in[11];
    const float* Wfc2  = (const float*)d_in[12];
    const float* bfc2  = (const float*)d_in[13];

    const int N = in_sizes[3];      // 100000
    const int E = in_sizes[2];      // 1600000
    const int* row = ei;
    const int* col = ei + E;

    char* ws = (char*)d_ws;
    float* dinv   = (float*)ws;              ws += align256((size_t)N * 4);
    int*   offs   = (int*)ws;                ws += align256((size_t)(N + 1) * 4);
    int*   bsums  = (int*)ws;                ws += align256((size_t)1024 * 4);
    int2*  perm   = (int2*)ws;               ws += align256((size_t)E * 8);
    float* bufA   = (float*)ws;              ws += align256((size_t)N * 128 * 4);  // agg f32 (conv3)
    ushort* bufH1 = (ushort*)ws;             ws += align256((size_t)N * 40 * 2);   // H1 bf16
    ushort* bufH2 = (ushort*)ws;             ws += align256((size_t)N * 80 * 2);   // H2 bf16
    ushort* xbf   = (ushort*)ws;             ws += align256((size_t)N * 40 * 2);   // x bf16
    float* g      = (float*)ws;              ws += align256((size_t)512 * 128 * 4);

    const int NB   = cdiv(N, 64);            // 1563 buckets (<= MAXNB)
    const int TOT  = NB * TB;                // (bucket, tile) cells = 400128
    const int chunkE = cdiv(E, TB);          // edges per tile = 6250
    const int nScanH = cdiv(TOT, SCHUNK);    // 391 (<= 1024)

    // transients aliased into bufA (51.2MB; all dead before gather3 writes bufA):
    // semi int2 (12.8MB) | gHist u32[TOT] (1.6MB) | scanned u32[TOT] (1.6MB)
    int2* semi = (int2*)bufA;
    unsigned int* gHist =
        (unsigned int*)((char*)bufA + align256((size_t)E * 8));
    unsigned int* scanned =
        (unsigned int*)((char*)gHist + align256((size_t)TOT * 4));

    const int B = 256;

    // --- atomic-free CSR build ---
    histA_kernel<<<TB, 512, 0, stream>>>(col, gHist, E, NB, chunkE,
                                         x, xbf, (long)N * 10);
    scanAH_kernel<<<nScanH, B, 0, stream>>>(gHist, bsums, TOT, NB);
    scanB_kernel<<<1, 1024, 0, stream>>>(bsums, offs, nScanH, N);
    scanCH_kernel<<<nScanH, B, 0, stream>>>(gHist, bsums, scanned, TOT, NB);
    scatterC_kernel<<<TB, 512, 0, stream>>>(row, col, ew, scanned, semi, E, NB, chunkE);
    fineD_kernel<<<NB, 256, 0, stream>>>(semi, scanned, offs, dinv, perm, E, N, NB);
    normE_kernel<<<cdiv(N, B), B, 0, stream>>>(offs, dinv, perm, N);

    // --- conv1 fused: H1 = relu((A*x)@W1 + b1) -> bufH1 (bf16) ---
    fused_conv_kernel<40, 40, 128, 320><<<cdiv(N, 128), 320, 0, stream>>>(
        offs, perm, xbf, dinv, W1, b1, bufH1, N);

    // --- conv2 fused: H2 = relu((A*H1)@W2 + b2) -> bufH2 (bf16) ---
    fused_conv_kernel<40, 80, 64, 320><<<cdiv(N, 64), 320, 0, stream>>>(
        offs, perm, bufH1, dinv, W2, b2, bufH2, N);

    // --- conv3: gather (R11) + col-split gemm/pool ---
    gather_kernel<80><<<cdiv((long)N * 20, B), B, 0, stream>>>(
        offs, perm, bufH2, dinv, bufA, N);
    hipMemsetAsync(g, 0, (size_t)512 * 128 * 4, stream);
    {
        dim3 grid(cdiv(N, 64), 2);
        gemm_pool_kernel<80, 128, 64, 256><<<grid, 256, 0, stream>>>(
            bufA, W3, b3, batch, (unsigned int*)g, N);
    }

    // --- MLP + softmax ---
    fc_kernel<<<512, 256, 0, stream>>>(g, Wfc1, bfc1, Wfc2, bfc2, (float*)d_out);
}

// Round 9
// 365.358 us; speedup vs baseline: 1.1213x; 1.0192x over previous
//
#include <hip/hip_runtime.h>

// ---------------------------------------------------------------------------
// GCNnet: 3x GCNConv (40->40->80->128) + global max pool + MLP(128->512->2) + softmax
// N=100000 nodes, E=1600000 edges, G=512 graphs.
// Round 17: gather3 (57us, fabric-bound, ALUs idle) + gemm_pool (~46us,
// ALU/latency-bound, memory idle) are complementary and round-trip 32MB bufA.
// Fuse conv3 fully: phase1 = gather 64 nodes x 80 feats into LDS (21.5KB);
// phase2 = 80->128 GEMM + hierarchical pool with W3 read from GLOBAL
// (coalesced float4, L1/L2-resident across 782 blocks) instead of 40KB LDS.
// Phase-2 agg LDS reads are wave broadcasts (free); blocks in phase1
// (memory wait) overlap blocks in phase2 (FMA) on the same CU.
// bufA round-trip eliminated; gemm_pool dispatch eliminated.
// ---------------------------------------------------------------------------

static inline int cdiv(long a, int b) { return (int)((a + b - 1) / b); }
static inline size_t align256(size_t x) { return (x + 255) & ~(size_t)255; }

#define FXSCALE 16777216.0f           // 2^24
#define SCHUNK  1024                  // elements per scan block
#define BKT_SHIFT 6                   // 64 nodes per bucket
#define MAXNB   2048                  // LDS histogram capacity (N <= 131072)
#define TB      256                   // histogram tiles

__device__ __forceinline__ float bf2f(unsigned short u) {
    return __uint_as_float(((unsigned int)u) << 16);
}
__device__ __forceinline__ unsigned short f2bf(float f) {   // round-nearest-even
    unsigned int u = __float_as_uint(f);
    return (unsigned short)((u + 0x7FFFu + ((u >> 16) & 1u)) >> 16);
}

#define ACC4(A, U, M)                                                         \
    do {                                                                      \
        A.x += bf2f((U).x) * (M); A.y += bf2f((U).y) * (M);                   \
        A.z += bf2f((U).z) * (M); A.w += bf2f((U).w) * (M);                   \
    } while (0)

// Pass A: per-tile LDS histogram over NB buckets (bucket = col>>6).
// gHist[tile][bucket]. Fused: x f32 -> bf16 (unpadded rows, stride 40).
__global__ __launch_bounds__(512)
void histA_kernel(const int* __restrict__ col, unsigned int* __restrict__ gHist,
                  int E, int NB, int chunk,
                  const float* __restrict__ x, ushort* __restrict__ xbf, long n4) {
    __shared__ unsigned int hist[MAXNB];
    int t = blockIdx.x;
    for (int i = threadIdx.x; i < NB; i += 512) hist[i] = 0u;
    __syncthreads();
    int s = t * chunk, e = min(s + chunk, E);
    for (int i = s + threadIdx.x; i < e; i += 512)
        atomicAdd(&hist[(unsigned int)col[i] >> BKT_SHIFT], 1u);
    // fused f2bf: i/10 = row, i%10 = float4 slot -> xbf[row*40 + slot*4]
    long gid = (long)t * 512 + threadIdx.x, gstride = (long)TB * 512;
    for (long i = gid; i < n4; i += gstride) {
        float4 v = ((const float4*)x)[i];
        long r = i / 10, c = i % 10;
        *(ushort4*)(xbf + r * 40 + c * 4) =
            make_ushort4(f2bf(v.x), f2bf(v.y), f2bf(v.z), f2bf(v.w));
    }
    __syncthreads();
    for (int b = threadIdx.x; b < NB; b += 512)
        gHist[(size_t)t * NB + b] = hist[b];
}

// scan phase A (histogram variant): per-block sums of the bucket-major view
// element i -> gHist[(i&255)*NB + (i>>8)]   (i = bucket*256 + tile)
__global__ void scanAH_kernel(const unsigned int* __restrict__ gHist,
                              int* __restrict__ blockSums, int TOT, int NB) {
    __shared__ int wred[4];
    int tid = threadIdx.x, lane = tid & 63, wid = tid >> 6;
    int i0 = blockIdx.x * SCHUNK + tid * 4;
    int s = 0;
#pragma unroll
    for (int k = 0; k < 4; ++k) {
        int i = i0 + k;
        if (i < TOT) s += (int)gHist[(size_t)(i & 255) * NB + (i >> 8)];
    }
#pragma unroll
    for (int off = 32; off > 0; off >>= 1) s += __shfl_down(s, off, 64);
    if (lane == 0) wred[wid] = s;
    __syncthreads();
    if (tid == 0) blockSums[blockIdx.x] = wred[0] + wred[1] + wred[2] + wred[3];
}

// scan phase B: one block, exclusive scan of blockSums[nb] (nb <= 1024);
// writes grand total into offs[N] (= E).
__global__ void scanB_kernel(int* __restrict__ blockSums, int* __restrict__ offs,
                             int nb, int N) {
    __shared__ int wsum[16];
    int tid = threadIdx.x, lane = tid & 63, wid = tid >> 6;
    int v = (tid < nb) ? blockSums[tid] : 0;
    int incl = v;
#pragma unroll
    for (int off = 1; off < 64; off <<= 1) {
        int t = __shfl_up(incl, off, 64);
        if (lane >= off) incl += t;
    }
    if (lane == 63) wsum[wid] = incl;
    __syncthreads();
    if (wid == 0 && lane < 16) {
        int w = wsum[lane];
        int ic = w;
#pragma unroll
        for (int off = 1; off < 16; off <<= 1) {
            int t = __shfl_up(ic, off, 64);
            if (lane >= off) ic += t;
        }
        wsum[lane] = ic - w;   // exclusive
    }
    __syncthreads();
    if (tid < nb) blockSums[tid] = wsum[wid] + incl - v;   // exclusive prefix
    if (tid == 1023) offs[N] = wsum[15] + incl;            // grand total
}

// scan phase C (histogram variant): local exclusive scan + block offset ->
// scanned[i] = global output cursor for (bucket = i>>8, tile = i&255)
__global__ void scanCH_kernel(const unsigned int* __restrict__ gHist,
                              const int* __restrict__ blockSums,
                              unsigned int* __restrict__ scanned, int TOT, int NB) {
    __shared__ int wsum[4];
    int tid = threadIdx.x, lane = tid & 63, wid = tid >> 6;
    int i0 = blockIdx.x * SCHUNK + tid * 4;
    int v0 = 0, v1 = 0, v2 = 0, v3 = 0;
    if (i0 + 0 < TOT) v0 = (int)gHist[(size_t)((i0 + 0) & 255) * NB + ((i0 + 0) >> 8)];
    if (i0 + 1 < TOT) v1 = (int)gHist[(size_t)((i0 + 1) & 255) * NB + ((i0 + 1) >> 8)];
    if (i0 + 2 < TOT) v2 = (int)gHist[(size_t)((i0 + 2) & 255) * NB + ((i0 + 2) >> 8)];
    if (i0 + 3 < TOT) v3 = (int)gHist[(size_t)((i0 + 3) & 255) * NB + ((i0 + 3) >> 8)];
    int sum = v0 + v1 + v2 + v3;
    int incl = sum;
#pragma unroll
    for (int off = 1; off < 64; off <<= 1) {
        int t = __shfl_up(incl, off, 64);
        if (lane >= off) incl += t;
    }
    if (lane == 63) wsum[wid] = incl;
    __syncthreads();
    if (tid == 0) {
        int c = 0;
#pragma unroll
        for (int k = 0; k < 4; ++k) { int t = wsum[k]; wsum[k] = c; c += t; }
    }
    __syncthreads();
    int pre = blockSums[blockIdx.x] + wsum[wid] + (incl - sum);
    if (i0 + 0 < TOT) scanned[i0 + 0] = (unsigned int)pre;
    if (i0 + 1 < TOT) scanned[i0 + 1] = (unsigned int)(pre + v0);
    if (i0 + 2 < TOT) scanned[i0 + 2] = (unsigned int)(pre + v0 + v1);
    if (i0 + 3 < TOT) scanned[i0 + 3] = (unsigned int)(pre + v0 + v1 + v2);
}

// Pass C: scatter edges into bucket-grouped semi[] via LDS cursors.
// semi[pos] = {row | (col&63)<<17, wbits} (int2, row < 2^17).
__global__ __launch_bounds__(512)
void scatterC_kernel(const int* __restrict__ row, const int* __restrict__ col,
                     const float* __restrict__ w,
                     const unsigned int* __restrict__ scanned,
                     int2* __restrict__ semi, int E, int NB, int chunk) {
    __shared__ unsigned int cur[MAXNB];
    int t = blockIdx.x;
    for (int b = threadIdx.x; b < NB; b += 512)
        cur[b] = scanned[(size_t)b * TB + t];
    __syncthreads();
    int s = t * chunk, e = min(s + chunk, E);
    for (int i = s + threadIdx.x; i < e; i += 512) {
        int c = col[i];
        unsigned int pos = atomicAdd(&cur[(unsigned int)c >> BKT_SHIFT], 1u);
        semi[pos] = make_int2(row[i] | ((c & 63) << 17), __float_as_int(w[i]));
    }
}

// Pass D: one block per bucket (64 nodes). Fine counting sort by c6,
// per-node weighted degree (fixed-point LDS atomics) -> perm {row,wbits},
// offs, dinv. All atomics LDS.
__global__ __launch_bounds__(256)
void fineD_kernel(const int2* __restrict__ semi, const unsigned int* __restrict__ scanned,
                  int* __restrict__ offs, float* __restrict__ dinv,
                  int2* __restrict__ perm, int E, int N, int NB) {
    __shared__ unsigned int cnt[64], cur[64], wsum[64];
    __shared__ int nodeOffs[64];
    int b = blockIdx.x, tid = threadIdx.x;
    int s = (int)scanned[(size_t)b * TB];
    int e = (b + 1 < NB) ? (int)scanned[(size_t)(b + 1) * TB] : E;
    if (tid < 64) { cnt[tid] = 0u; wsum[tid] = 0u; }
    __syncthreads();
    for (int i = s + tid; i < e; i += 256) {
        int2 v = semi[i];
        int c6 = (v.x >> 17) & 63;
        atomicAdd(&cnt[c6], 1u);
        atomicAdd(&wsum[c6], (unsigned int)llrintf(__int_as_float(v.y) * FXSCALE));
    }
    __syncthreads();
    if (tid < 64) {
        int v = (int)cnt[tid];
        int incl = v;
#pragma unroll
        for (int off = 1; off < 64; off <<= 1) {
            int u = __shfl_up(incl, off, 64);
            if (tid >= off) incl += u;
        }
        nodeOffs[tid] = incl - v;          // exclusive within bucket
        cur[tid] = (unsigned int)(incl - v);
    }
    __syncthreads();
    for (int i = s + tid; i < e; i += 256) {
        int2 v = semi[i];
        int c6 = (v.x >> 17) & 63;
        unsigned int r = atomicAdd(&cur[c6], 1u);
        perm[s + (int)r] = make_int2(v.x & 0x1FFFF, v.y);   // {row, wbits}
    }
    if (tid < 64) {
        int node = (b << BKT_SHIFT) + tid;
        if (node < N) {
            offs[node] = s + nodeOffs[tid];
            float deg = (float)wsum[tid] * (1.0f / FXSCALE);
            dinv[node] = rsqrtf(deg + 1.0f);
        }
    }
    if (b == NB - 1 && tid == 0) offs[N] = E;
}

// Pass E: perm.y = dinv[row] * w * dinv[col]  (thread per destination node)
__global__ void normE_kernel(const int* __restrict__ offs, const float* __restrict__ dinv,
                             int2* __restrict__ perm, int N) {
    int n = blockIdx.x * blockDim.x + threadIdx.x;
    if (n >= N) return;
    int s = offs[n], e = offs[n + 1];
    float dc = dinv[n];
    for (int j = s; j < e; ++j) {
        int2 p = perm[j];
        float nm = dinv[p.x] * __int_as_float(p.y) * dc;
        perm[j] = make_int2(p.x, __float_as_int(nm));
    }
}

// Fused conv (conv1/conv2): phase1 = R11 gather into LDS agg (rows padded to
// K+4 floats vs phase-2 bank conflicts); sync; phase2 = gemm from LDS, relu,
// bf16 out. Removes the bufA global round-trip entirely.
template<int K, int FOUT, int NPB, int BLK>
__global__ __launch_bounds__(BLK)
void fused_conv_kernel(const int* __restrict__ offs, const int2* __restrict__ perm,
                       const ushort* __restrict__ H, const float* __restrict__ dinv,
                       const float* __restrict__ W, const float* __restrict__ bias,
                       ushort* __restrict__ out, int N) {
    constexpr int TPN = K / 4;
    constexpr int TPQ = FOUT / 4;
    constexpr int NPT = 4;
    constexpr int KP = K + 4;              // padded agg row (floats)
    static_assert((NPB * TPN) % BLK == 0, "phase1 tiling");
    static_assert((NPB / NPT) * TPQ == BLK, "phase2 tiling");
    __shared__ float wsm[K * FOUT];
    __shared__ float aggs[NPB * KP];
    for (int i = threadIdx.x; i < K * FOUT; i += BLK) wsm[i] = W[i];

    // ---- phase 1: gather into LDS ----
#pragma unroll
    for (int p0 = 0; p0 < NPB * TPN; p0 += BLK) {
        int p = p0 + threadIdx.x;
        int nl = p / TPN, q = p % TPN;
        int node = blockIdx.x * NPB + nl;
        float4 a0 = make_float4(0.f, 0.f, 0.f, 0.f);
        float4 a1 = make_float4(0.f, 0.f, 0.f, 0.f);
        if (node < N) {
            int s = offs[node], e = offs[node + 1];
            int j = s;
            for (; j + 4 <= e; j += 4) {
                int2 p0e = perm[j + 0], p1e = perm[j + 1];
                int2 p2e = perm[j + 2], p3e = perm[j + 3];
                ushort4 u0 = *(const ushort4*)(H + (long)p0e.x * K + q * 4);
                ushort4 u1 = *(const ushort4*)(H + (long)p1e.x * K + q * 4);
                ushort4 u2 = *(const ushort4*)(H + (long)p2e.x * K + q * 4);
                ushort4 u3 = *(const ushort4*)(H + (long)p3e.x * K + q * 4);
                ACC4(a0, u0, __int_as_float(p0e.y));
                ACC4(a1, u1, __int_as_float(p1e.y));
                ACC4(a0, u2, __int_as_float(p2e.y));
                ACC4(a1, u3, __int_as_float(p3e.y));
            }
            for (; j < e; ++j) {
                int2 pe = perm[j];
                ushort4 u = *(const ushort4*)(H + (long)pe.x * K + q * 4);
                ACC4(a0, u, __int_as_float(pe.y));
            }
            float di = dinv[node], d2 = di * di;
            ushort4 su = *(const ushort4*)(H + (long)node * K + q * 4);
            ACC4(a0, su, d2);
        }
        a0.x += a1.x; a0.y += a1.y; a0.z += a1.z; a0.w += a1.w;
        *(float4*)&aggs[nl * KP + q * 4] = a0;
    }
    __syncthreads();

    // ---- phase 2: gemm from LDS ----
    int q = threadIdx.x % TPQ, pg = threadIdx.x / TPQ;
    long nbase = (long)blockIdx.x * NPB + (long)pg * NPT;
    float4 acc[NPT];
#pragma unroll
    for (int t = 0; t < NPT; ++t) acc[t] = make_float4(0.f, 0.f, 0.f, 0.f);
    const float* wq = wsm + q * 4;
#pragma unroll 4
    for (int i = 0; i < K / 4; ++i) {
        float4 xv[NPT];
#pragma unroll
        for (int t = 0; t < NPT; ++t)
            xv[t] = *(const float4*)&aggs[(pg * NPT + t) * KP + i * 4];
#pragma unroll
        for (int j = 0; j < 4; ++j) {
            float4 wv = *(const float4*)(wq + (i * 4 + j) * FOUT);
#pragma unroll
            for (int t = 0; t < NPT; ++t) {
                float v = ((const float*)&xv[t])[j];
                acc[t].x += v * wv.x; acc[t].y += v * wv.y;
                acc[t].z += v * wv.z; acc[t].w += v * wv.w;
            }
        }
    }
    float4 bv = *(const float4*)(bias + q * 4);
#pragma unroll
    for (int t = 0; t < NPT; ++t) {
        long n = nbase + t;
        if (n < N) {
            float ox = fmaxf(acc[t].x + bv.x, 0.f);
            float oy = fmaxf(acc[t].y + bv.y, 0.f);
            float oz = fmaxf(acc[t].z + bv.z, 0.f);
            float ow = fmaxf(acc[t].w + bv.w, 0.f);
            *(ushort4*)(out + n * FOUT + q * 4) =
                make_ushort4(f2bf(ox), f2bf(oy), f2bf(oz), f2bf(ow));
        }
    }
}

// Fused conv3 + pool: phase1 = gather NPB=64 nodes x 80 feats into LDS
// (21.5KB); phase2 = 80->128 gemm with W3 from GLOBAL (coalesced, L1/L2-hot
// across all blocks) + relu + hierarchical max-pool. NPT=8, TPQ=32.
template<int K, int FOUT, int NPB, int BLK>
__global__ __launch_bounds__(BLK)
void fused_conv3_pool_kernel(const int* __restrict__ offs, const int2* __restrict__ perm,
                             const ushort* __restrict__ H, const float* __restrict__ dinv,
                             const float* __restrict__ W, const float* __restrict__ bias,
                             const int* __restrict__ batch,
                             unsigned int* __restrict__ g, int N) {
    constexpr int TPN = K / 4;             // 20
    constexpr int TPQ = FOUT / 4;          // 32
    constexpr int NPT = NPB / (BLK / TPQ); // 64 / 8 = 8
    constexpr int KP = K + 4;              // padded agg row (floats)
    static_assert((NPB * TPN) % BLK == 0, "phase1 tiling");
    static_assert((NPB / NPT) * TPQ == BLK, "phase2 tiling");
    __shared__ float aggs[NPB * KP];
    __shared__ unsigned int gma[2 * FOUT];
    __shared__ int gfirst;
    if (threadIdx.x == 0) gfirst = batch[min((int)(blockIdx.x * NPB), N - 1)];
    for (int i = threadIdx.x; i < 2 * FOUT; i += BLK) gma[i] = 0u;

    // ---- phase 1: gather into LDS ----
#pragma unroll
    for (int p0 = 0; p0 < NPB * TPN; p0 += BLK) {
        int p = p0 + threadIdx.x;
        int nl = p / TPN, q = p % TPN;
        int node = blockIdx.x * NPB + nl;
        float4 a0 = make_float4(0.f, 0.f, 0.f, 0.f);
        float4 a1 = make_float4(0.f, 0.f, 0.f, 0.f);
        if (node < N) {
            int s = offs[node], e = offs[node + 1];
            int j = s;
            for (; j + 4 <= e; j += 4) {
                int2 p0e = perm[j + 0], p1e = perm[j + 1];
                int2 p2e = perm[j + 2], p3e = perm[j + 3];
                ushort4 u0 = *(const ushort4*)(H + (long)p0e.x * K + q * 4);
                ushort4 u1 = *(const ushort4*)(H + (long)p1e.x * K + q * 4);
                ushort4 u2 = *(const ushort4*)(H + (long)p2e.x * K + q * 4);
                ushort4 u3 = *(const ushort4*)(H + (long)p3e.x * K + q * 4);
                ACC4(a0, u0, __int_as_float(p0e.y));
                ACC4(a1, u1, __int_as_float(p1e.y));
                ACC4(a0, u2, __int_as_float(p2e.y));
                ACC4(a1, u3, __int_as_float(p3e.y));
            }
            for (; j < e; ++j) {
                int2 pe = perm[j];
                ushort4 u = *(const ushort4*)(H + (long)pe.x * K + q * 4);
                ACC4(a0, u, __int_as_float(pe.y));
            }
            float di = dinv[node], d2 = di * di;
            ushort4 su = *(const ushort4*)(H + (long)node * K + q * 4);
            ACC4(a0, su, d2);
        }
        a0.x += a1.x; a0.y += a1.y; a0.z += a1.z; a0.w += a1.w;
        *(float4*)&aggs[nl * KP + q * 4] = a0;
    }
    __syncthreads();

    // ---- phase 2: gemm (W from global) + pool ----
    int q = threadIdx.x % TPQ, pg = threadIdx.x / TPQ;
    long nbase = (long)blockIdx.x * NPB + (long)pg * NPT;
    float4 acc[NPT];
#pragma unroll
    for (int t = 0; t < NPT; ++t) acc[t] = make_float4(0.f, 0.f, 0.f, 0.f);
    const float* wq = W + q * 4;
#pragma unroll 4
    for (int i = 0; i < K / 4; ++i) {
        float4 xv[NPT];
#pragma unroll
        for (int t = 0; t < NPT; ++t)
            xv[t] = *(const float4*)&aggs[(pg * NPT + t) * KP + i * 4];
#pragma unroll
        for (int j = 0; j < 4; ++j) {
            float4 wv = *(const float4*)(wq + (i * 4 + j) * FOUT);
#pragma unroll
            for (int t = 0; t < NPT; ++t) {
                float v = ((const float*)&xv[t])[j];
                acc[t].x += v * wv.x; acc[t].y += v * wv.y;
                acc[t].z += v * wv.z; acc[t].w += v * wv.w;
            }
        }
    }
    float4 bv = *(const float4*)(bias + q * 4);
#pragma unroll
    for (int t = 0; t < NPT; ++t) {
        long n = nbase + t;
        if (n < N) {
            unsigned int bx = __float_as_uint(fmaxf(acc[t].x + bv.x, 0.f));
            unsigned int by = __float_as_uint(fmaxf(acc[t].y + bv.y, 0.f));
            unsigned int bz = __float_as_uint(fmaxf(acc[t].z + bv.z, 0.f));
            unsigned int bw = __float_as_uint(fmaxf(acc[t].w + bv.w, 0.f));
            int rel = batch[n] - gfirst;
            if (rel < 2) {
                unsigned int* d = gma + rel * FOUT + q * 4;
                atomicMax(d + 0, bx); atomicMax(d + 1, by);
                atomicMax(d + 2, bz); atomicMax(d + 3, bw);
            } else {
                unsigned int* d = g + (long)batch[n] * FOUT + q * 4;
                atomicMax(d + 0, bx); atomicMax(d + 1, by);
                atomicMax(d + 2, bz); atomicMax(d + 3, bw);
            }
        }
    }
    __syncthreads();
    for (int i = threadIdx.x; i < 2 * FOUT; i += BLK) {
        unsigned int v = gma[i];
        if (v) atomicMax(&g[(long)(gfirst + i / FOUT) * FOUT + (i % FOUT)], v);
    }
}

// one block per graph: relu(g@Wfc1+bfc1) @ Wfc2 + bfc2 -> softmax
__global__ void fc_kernel(const float* __restrict__ g, const float* __restrict__ Wfc1,
                          const float* __restrict__ bfc1, const float* __restrict__ Wfc2,
                          const float* __restrict__ bfc2, float* __restrict__ out) {
    __shared__ float gs[128];
    __shared__ float red0[256], red1[256];
    int b = blockIdx.x, tid = threadIdx.x;
    if (tid < 128) gs[tid] = g[b * 128 + tid];
    __syncthreads();
    float h0 = bfc1[tid], h1 = bfc1[tid + 256];
    for (int k = 0; k < 128; ++k) {
        float gv = gs[k];
        h0 += gv * Wfc1[k * 512 + tid];
        h1 += gv * Wfc1[k * 512 + tid + 256];
    }
    h0 = fmaxf(h0, 0.f); h1 = fmaxf(h1, 0.f);
    red0[tid] = h0 * Wfc2[tid * 2 + 0] + h1 * Wfc2[(tid + 256) * 2 + 0];
    red1[tid] = h0 * Wfc2[tid * 2 + 1] + h1 * Wfc2[(tid + 256) * 2 + 1];
    __syncthreads();
    for (int s = 128; s > 0; s >>= 1) {
        if (tid < s) { red0[tid] += red0[tid + s]; red1[tid] += red1[tid + s]; }
        __syncthreads();
    }
    if (tid == 0) {
        float L0 = red0[0] + bfc2[0], L1 = red1[0] + bfc2[1];
        float m = fmaxf(L0, L1);
        float e0 = expf(L0 - m), e1 = expf(L1 - m);
        float inv = 1.f / (e0 + e1);
        out[b * 2 + 0] = e0 * inv;
        out[b * 2 + 1] = e1 * inv;
    }
}

extern "C" void kernel_launch(void* const* d_in, const int* in_sizes, int n_in,
                              void* d_out, int out_size, void* d_ws, size_t ws_size,
                              hipStream_t stream) {
    const float* x     = (const float*)d_in[0];
    const int*   ei    = (const int*)d_in[1];
    const float* ew    = (const float*)d_in[2];
    const int*   batch = (const int*)d_in[3];
    const float* W1    = (const float*)d_in[4];
    const float* b1    = (const float*)d_in[5];
    const float* W2    = (const float*)d_in[6];
    const float* b2    = (const float*)d_in[7];
    const float* W3    = (const float*)d_in[8];
    const float* b3    = (const float*)d_in[9];
    const float* Wfc1  = (const float*)d_in[10];
    const float* bfc1  = (const float*)d_in[11];
    const float* Wfc2  = (const float*)d_in[12];
    const float* bfc2  = (const float*)d_in[13];

    const int N = in_sizes[3];      // 100000
    const int E = in_sizes[2];      // 1600000
    const int* row = ei;
    const int* col = ei + E;

    char* ws = (char*)d_ws;
    float* dinv   = (float*)ws;              ws += align256((size_t)N * 4);
    int*   offs   = (int*)ws;                ws += align256((size_t)(N + 1) * 4);
    int*   bsums  = (int*)ws;                ws += align256((size_t)1024 * 4);
    int2*  perm   = (int2*)ws;               ws += align256((size_t)E * 8);
    float* bufA   = (float*)ws;              ws += align256((size_t)N * 128 * 4);  // build transients
    ushort* bufH1 = (ushort*)ws;             ws += align256((size_t)N * 40 * 2);   // H1 bf16
    ushort* bufH2 = (ushort*)ws;             ws += align256((size_t)N * 80 * 2);   // H2 bf16
    ushort* xbf   = (ushort*)ws;             ws += align256((size_t)N * 40 * 2);   // x bf16
    float* g      = (float*)ws;              ws += align256((size_t)512 * 128 * 4);

    const int NB   = cdiv(N, 64);            // 1563 buckets (<= MAXNB)
    const int TOT  = NB * TB;                // (bucket, tile) cells = 400128
    const int chunkE = cdiv(E, TB);          // edges per tile = 6250
    const int nScanH = cdiv(TOT, SCHUNK);    // 391 (<= 1024)

    // transients aliased into bufA (51.2MB; all dead before convs):
    // semi int2 (12.8MB) | gHist u32[TOT] (1.6MB) | scanned u32[TOT] (1.6MB)
    int2* semi = (int2*)bufA;
    unsigned int* gHist =
        (unsigned int*)((char*)bufA + align256((size_t)E * 8));
    unsigned int* scanned =
        (unsigned int*)((char*)gHist + align256((size_t)TOT * 4));

    const int B = 256;

    // --- atomic-free CSR build ---
    histA_kernel<<<TB, 512, 0, stream>>>(col, gHist, E, NB, chunkE,
                                         x, xbf, (long)N * 10);
    scanAH_kernel<<<nScanH, B, 0, stream>>>(gHist, bsums, TOT, NB);
    scanB_kernel<<<1, 1024, 0, stream>>>(bsums, offs, nScanH, N);
    scanCH_kernel<<<nScanH, B, 0, stream>>>(gHist, bsums, scanned, TOT, NB);
    scatterC_kernel<<<TB, 512, 0, stream>>>(row, col, ew, scanned, semi, E, NB, chunkE);
    fineD_kernel<<<NB, 256, 0, stream>>>(semi, scanned, offs, dinv, perm, E, N, NB);
    normE_kernel<<<cdiv(N, B), B, 0, stream>>>(offs, dinv, perm, N);

    // --- conv1 fused: H1 = relu((A*x)@W1 + b1) -> bufH1 (bf16) ---
    fused_conv_kernel<40, 40, 128, 320><<<cdiv(N, 128), 320, 0, stream>>>(
        offs, perm, xbf, dinv, W1, b1, bufH1, N);

    // --- conv2 fused: H2 = relu((A*H1)@W2 + b2) -> bufH2 (bf16) ---
    fused_conv_kernel<40, 80, 64, 320><<<cdiv(N, 64), 320, 0, stream>>>(
        offs, perm, bufH1, dinv, W2, b2, bufH2, N);

    // --- conv3 fused: pool(relu((A*H2)@W3 + b3)) -> g ---
    hipMemsetAsync(g, 0, (size_t)512 * 128 * 4, stream);
    fused_conv3_pool_kernel<80, 128, 64, 256><<<cdiv(N, 64), 256, 0, stream>>>(
        offs, perm, bufH2, dinv, W3, b3, batch, (unsigned int*)g, N);

    // --- MLP + softmax ---
    fc_kernel<<<512, 256, 0, stream>>>(g, Wfc1, bfc1, Wfc2, bfc2, (float*)d_out);
}